// Round 5
// baseline (6561.492 us; speedup 1.0000x reference)
//
#include <hip/hip_runtime.h>
#include <hip/hip_bf16.h>

typedef _Float16 f16x2 __attribute__((ext_vector_type(2)));

#define HID 300
#define NSEQ 64
#define NROWS 4096   // B*N = 64*64

__device__ __forceinline__ float sigm(float x){ return 1.f/(1.f+__expf(-x)); }

__device__ __forceinline__ float fdot2a(f16x2 a, f16x2 b, float c){
#if __has_builtin(__builtin_amdgcn_fdot2)
  return __builtin_amdgcn_fdot2(a, b, c, false);
#else
  return c + (float)a.x*(float)b.x + (float)a.y*(float)b.y;
#endif
}

// Relaxed agent-scope helpers: sc-flagged (LLC-coherent) but NO cache
// maintenance (no buffer_inv / wbl2) -> XCD L2 stays warm. [R3 lesson]
__device__ __forceinline__ void xstore(float* p, float v){
  __hip_atomic_store(p, v, __ATOMIC_RELAXED, __HIP_MEMORY_SCOPE_AGENT);
}
__device__ __forceinline__ float xload(const float* p){
  return __hip_atomic_load(p, __ATOMIC_RELAXED, __HIP_MEMORY_SCOPE_AGENT);
}

// ---------------------------------------------------------------------------
// Serial-path weight repack: f32 -> fp16 pairs, [kg][outs][4 pairs] layout.
// W_M4: per layer [38][1800][4]; rows 0..899 = whh_c, 900..1799 = wih_p.
// WrT4: per layer [38][600][4]; row t = d*2+hh (hh=0 -> wr0 row d, 1 -> wr1).
// ---------------------------------------------------------------------------
__global__ void convert_kernel(const float* __restrict__ whh_c, const float* __restrict__ wih_p,
    const float* __restrict__ wr0, const float* __restrict__ wr1,
    f16x2* __restrict__ W_M4, f16x2* __restrict__ WrT4)
{
  const int NA = 4*38*1800*4;
  const int NB = 4*38*600*4;
  for (int idx = blockIdx.x*blockDim.x + threadIdx.x; idx < NA+NB; idx += gridDim.x*blockDim.x){
    if (idx < NA){
      int l    = idx/(38*1800*4);
      int rem  = idx - l*(38*1800*4);
      int kg   = rem/(1800*4);
      int rem2 = rem - kg*(1800*4);
      int o = rem2>>2, s = rem2&3;
      int c = (kg*4+s)*2;
      float v0=0.f, v1=0.f;
      if (c < 300){
        const float* src = (o<900) ? (whh_c + ((size_t)l*900+o)*300)
                                   : (wih_p + ((size_t)l*900+(o-900))*300);
        v0 = src[c]; v1 = src[c+1];
      }
      f16x2 t; t.x=(_Float16)v0; t.y=(_Float16)v1;
      W_M4[idx] = t;
    } else {
      int j    = idx - NA;
      int l    = j/(38*600*4);
      int rem  = j - l*(38*600*4);
      int kg   = rem/(600*4);
      int rem2 = rem - kg*(600*4);
      int t6 = rem2>>2, s = rem2&3;
      int d = t6>>1, hh = t6&1;
      int c = (kg*4+s)*2;
      float v0=0.f, v1=0.f;
      if (c < 300){
        const float* src = hh ? (wr1 + ((size_t)l*300+d)*300)
                              : (wr0 + ((size_t)l*300+d)*300);
        v0 = src[c]; v1 = src[c+1];
      }
      f16x2 t; t.x=(_Float16)v0; t.y=(_Float16)v1;
      WrT4[j] = t;
    }
  }
}

// ---------------------------------------------------------------------------
// Head weight repack + per-launch zeroing of sync counters.
// ---------------------------------------------------------------------------
__global__ void convert_head_kernel(const float* __restrict__ w1, const float* __restrict__ w2,
    f16x2* __restrict__ W_14, f16x2* __restrict__ W_24, int* __restrict__ syncc)
{
  const int N1 = 318*304*4;
  const int N2 = 38*304*4;
  const int NS = 4*64*64;
  for (int idx = blockIdx.x*blockDim.x + threadIdx.x; idx < N1+N2+NS; idx += gridDim.x*blockDim.x){
    if (idx < N1){
      int kgg = idx/(304*4);
      int rem = idx - kgg*(304*4);
      int o = rem>>2, s = rem&3;
      int segbase, seglen, kgl;
      if (kgg < 190){ int seg = kgg/38; kgl = kgg - seg*38; segbase = seg*300; seglen = 300; }
      else { int kk = kgg-190; int sf = kk>>6; kgl = kk&63; segbase = 1500 + sf*512; seglen = 512; }
      int c = (kgl*4+s)*2;
      float v0=0.f, v1=0.f;
      if (o < 300 && c < seglen){
        v0 = w1[(size_t)o*2524 + segbase + c];
        if (c+1 < seglen) v1 = w1[(size_t)o*2524 + segbase + c + 1];
      }
      f16x2 t; t.x=(_Float16)v0; t.y=(_Float16)v1;
      W_14[idx] = t;
    } else if (idx < N1+N2){
      int j = idx - N1;
      int kg = j/(304*4);
      int rem = j - kg*(304*4);
      int o = rem>>2, s = rem&3;
      int c = (kg*4+s)*2;
      float v0=0.f, v1=0.f;
      if (o < 300 && c < 300){ v0 = w2[(size_t)o*300+c]; v1 = w2[(size_t)o*300+c+1]; }
      f16x2 t; t.x=(_Float16)v0; t.y=(_Float16)v1;
      W_24[j] = t;
    } else {
      syncc[idx - N1 - N2] = 0;
    }
  }
}

// ---------------------------------------------------------------------------
// H0 = relu(features @ w_in^T + b_in)
// ---------------------------------------------------------------------------
__global__ __launch_bounds__(256) void h0_kernel(const float* __restrict__ feat,
    const float* __restrict__ w_in, const float* __restrict__ b_in, float* __restrict__ H0)
{
  const int tid = threadIdx.x;
  const int r0  = blockIdx.x*16;
  __shared__ float X[16*512];
  float acc[2][16];
  #pragma unroll
  for (int a=0;a<2;a++)
    #pragma unroll
    for (int r=0;r<16;r++) acc[a][r]=0.f;

  for (int c=0;c<2;c++){
    for (int t=tid; t<16*512; t+=256){
      int r=t>>9, k=t&511;
      X[t] = feat[(size_t)(r0+r)*1024 + c*512 + k];
    }
    __syncthreads();
    #pragma unroll
    for (int oo=0;oo<2;oo++){
      int o = tid + oo*256;
      if (o < HID){
        const float* wrow = w_in + (size_t)o*1024 + c*512;
        for (int k=0;k<512;k+=4){
          float4 w = *(const float4*)(wrow+k);
          #pragma unroll
          for (int r=0;r<16;r++)
            acc[oo][r] += w.x*X[r*512+k] + w.y*X[r*512+k+1]
                        + w.z*X[r*512+k+2] + w.w*X[r*512+k+3];
        }
      }
    }
    __syncthreads();
  }
  #pragma unroll
  for (int oo=0;oo<2;oo++){
    int o = tid + oo*256;
    if (o < HID){
      float bb = b_in[o];
      for (int r=0;r<16;r++)
        H0[(size_t)(r0+r)*HID + o] = fmaxf(acc[oo][r]+bb, 0.f);
    }
  }
}

// ---------------------------------------------------------------------------
// Per-layer precompute, 4-outs-per-thread register blocking (LDS reads /4).
// pre[row][0..899]=wih_c@Hin+bih_c, [900..1799]=whh_p@Hin+bhh_p, qd=wq.Hin
// ---------------------------------------------------------------------------
__global__ __launch_bounds__(256) void pre_kernel(const float* __restrict__ Hin,
    float* __restrict__ pre, float* __restrict__ qd,
    const float* __restrict__ wih_c, const float* __restrict__ whh_p,
    const float* __restrict__ bih_c, const float* __restrict__ bhh_p,
    const float* __restrict__ wq)
{
  const int tid = threadIdx.x;
  const int r0  = blockIdx.x*16;
  __shared__ float X[16*304];
  for (int t=tid; t<16*HID; t+=256){
    int r=t/HID, k=t-r*HID;
    X[r*304+k] = Hin[(size_t)(r0+r)*HID + k];
  }
  __syncthreads();
  if (tid < 16){
    float s=0.f; const float* x=&X[tid*304];
    for (int k=0;k<HID;k++) s += wq[k]*x[k];
    qd[r0+tid] = s;
  }
  for (int ob=0; ob<1800; ob+=1024){
    const float* wp[4]; float bias[4]; bool val[4]; int oo[4];
    #pragma unroll
    for (int q=0;q<4;q++){
      int o = ob + q*256 + tid;
      val[q] = (o < 1800); oo[q] = o;
      int oc = val[q] ? o : 0;
      if (oc < 900){ wp[q] = wih_c + (size_t)oc*HID;       bias[q] = val[q]? bih_c[oc] : 0.f; }
      else         { wp[q] = whh_p + (size_t)(oc-900)*HID; bias[q] = val[q]? bhh_p[oc-900] : 0.f; }
    }
    float acc[4][16];
    #pragma unroll
    for (int q=0;q<4;q++)
      #pragma unroll
      for (int r=0;r<16;r++) acc[q][r]=0.f;
    for (int k=0;k<HID;k+=4){
      float4 w0 = *(const float4*)(wp[0]+k);
      float4 w1 = *(const float4*)(wp[1]+k);
      float4 w2 = *(const float4*)(wp[2]+k);
      float4 w3 = *(const float4*)(wp[3]+k);
      #pragma unroll
      for (int r=0;r<16;r++){
        float4 x = *(const float4*)&X[r*304+k];
        acc[0][r] += w0.x*x.x + w0.y*x.y + w0.z*x.z + w0.w*x.w;
        acc[1][r] += w1.x*x.x + w1.y*x.y + w1.z*x.z + w1.w*x.w;
        acc[2][r] += w2.x*x.x + w2.y*x.y + w2.z*x.z + w2.w*x.w;
        acc[3][r] += w3.x*x.x + w3.y*x.y + w3.z*x.z + w3.w*x.w;
      }
    }
    #pragma unroll
    for (int q=0;q<4;q++)
      if (val[q])
        for (int r=0;r<16;r++)
          pre[(size_t)(r0+r)*1800 + oo[q]] = acc[q][r] + bias[q];
  }
}

// ---------------------------------------------------------------------------
// Sequential scan: 4 WGs per chain (256 WGs x 512 thr), slices exchange the
// gates GEMV through the LLC with relaxed-only atomics (no L2 flushes).
// ---------------------------------------------------------------------------
__global__ __launch_bounds__(512) void scan_kernel(
  const float* __restrict__ Hin, float* __restrict__ Hout,
  const float* __restrict__ pre, const float* __restrict__ qd,
  const f16x2* __restrict__ Wm, const f16x2* __restrict__ Wrt,
  const float* __restrict__ bhh_c, const float* __restrict__ bih_p,
  const float* __restrict__ wk, const float* __restrict__ gat_b, int layer,
  const int* __restrict__ speakers, float* __restrict__ xchg, int* __restrict__ syncc)
{
  __shared__ _Float16 Hh[NSEQ][304];
  __shared__ float gates[1800];
  __shared__ float Mf[HID];
  __shared__ f16x2 Mh[152];
  __shared__ f16x2 u01h[304];
  __shared__ float partM[600];
  __shared__ float wgt[NSEQ];
  __shared__ float kd[NSEQ];
  __shared__ float qs[NSEQ];
  __shared__ float red[320];
  __shared__ int   spk[NSEQ];
  __shared__ int   startA[NSEQ];

  const int tid   = threadIdx.x;
  const int chain = blockIdx.x & 63;
  const int sl    = blockIdx.x >> 6;   // slice 0..3: gates rows [450*sl, 450*sl+450)
  const int base  = chain*NSEQ;
  const float* preB = pre + (size_t)base*1800;
  const float* HinB = Hin + (size_t)base*HID;
  float* HoutB      = Hout + (size_t)base*HID;
  const uint4* Wm4  = (const uint4*)Wm;
  const uint4* Wr4  = (const uint4*)Wrt;
  const float gb = gat_b[layer];
  int*   cnt = syncc + ((size_t)layer*64 + chain)*64;
  float* xb0 = xchg + (size_t)chain*3648;   // 2 x 1824

  float bcr=0,bcz=0,bcn=0,bpr=0,bpz=0,bpn=0,wkv=0;
  if (tid < HID){
    bcr=bhh_c[tid]; bcz=bhh_c[300+tid]; bcn=bhh_c[600+tid];
    bpr=bih_p[tid]; bpz=bih_p[300+tid]; bpn=bih_p[600+tid];
    wkv=wk[tid];
  }
  if (tid < NSEQ){ spk[tid] = speakers[base+tid]; qs[tid] = qd[base+tid]; }
  if (tid >= 300 && tid < 320) red[tid] = 0.f;
  if (tid >= 300 && tid < 304){
    ((_Float16*)Mh)[tid]        = (_Float16)0.f;
    ((_Float16*)u01h)[tid]      = (_Float16)0.f;
    ((_Float16*)u01h)[304+tid]  = (_Float16)0.f;
  }
  __syncthreads();
  if (tid < NSEQ){
    int s = 0;
    for (int j=tid-1; j>=0; --j) if (spk[j]==spk[tid]){ s=j; break; }
    startA[tid] = s;
  }
  // i = 0 : C0 = GRU(x0, 0), P0 = GRU(0, x0)
  if (tid < HID){
    const float* p0 = preB;
    float r  = sigm(p0[tid] + bcr);
    float z  = sigm(p0[300+tid] + bcz);
    float n  = tanhf(p0[600+tid] + r*bcn);
    float C0 = (1.f-z)*n;
    float rp = sigm(bpr + p0[900+tid]);
    float zp = sigm(bpz + p0[1200+tid]);
    float np = tanhf(bpn + rp*p0[1500+tid]);
    float x0 = HinB[tid];
    float P0 = (1.f-zp)*np + zp*x0;
    float h  = C0 + P0;
    if (sl==0) HoutB[tid] = h;
    Hh[0][tid] = (_Float16)h;
    red[tid]   = h*wkv;
  }
  __syncthreads();
  if (tid < 64){
    float s = red[tid]+red[tid+64]+red[tid+128]+red[tid+192]+red[tid+256];
    #pragma unroll
    for (int o=32;o>0;o>>=1) s += __shfl_xor(s,o);
    if (tid==0) kd[0]=s;
  }

  for (int i=1; i<NSEQ; ++i){
    // prefetch pre row i + Hin row i (consumed only in GRU phase E)
    float pr0=0,pr1=0,pr2=0,pr3=0,pr4=0,pr5=0,qv=0;
    if (tid < HID){
      const float* p = preB + (size_t)i*1800;
      pr0=p[tid]; pr1=p[300+tid]; pr2=p[600+tid];
      pr3=p[900+tid]; pr4=p[1200+tid]; pr5=p[1500+tid];
      qv = HinB[(size_t)i*HID + tid];
    }
    __syncthreads();
    // A: masked softmax (one wave)
    if (tid < 64){
      const int st = startA[i];
      const bool in = (tid>=st) && (tid<i);
      const float q = qs[i];
      float a = in ? (q + kd[tid] + gb) : -3.0e38f;
      float m = a;
      #pragma unroll
      for (int o=32;o>0;o>>=1) m = fmaxf(m, __shfl_xor(m,o));
      float e = in ? __expf(a-m) : 0.f;
      float ssum = e;
      #pragma unroll
      for (int o=32;o>0;o>>=1) ssum += __shfl_xor(ssum,o);
      wgt[tid] = e/ssum;
    }
    __syncthreads();
    // B: u0 (same-speaker) / u1 (other-speaker) weighted history sums
    {
      const int st = startA[i]; const int ms = spk[i];
      #pragma unroll
      for (int pass=0; pass<2; pass++){
        int t = tid + pass*512;
        if (t < 600){
          const int d  = (t<300)? t : (t-300);
          const int wh = (t>=300);
          float u=0.f;
          for (int j=st;j<i;++j){
            float sel = ((spk[j]==ms) != (wh!=0)) ? 1.f : 0.f;
            u += sel*wgt[j]*(float)Hh[j][d];
          }
          ((_Float16*)u01h)[(wh?304:0) + d] = (_Float16)u;
        }
      }
    }
    __syncthreads();
    // C: partial M = wr0@u0 + wr1@u1 (600 rows), replicated
    {
      #pragma unroll
      for (int pass=0; pass<2; pass++){
        int t = tid + pass*512;
        if (t < 600){
          const int hh = t&1;
          const f16x2* uu = (const f16x2*)u01h + hh*152;
          float a0=0,a1=0,a2=0,a3=0;
          for (int kg=0;kg<38;kg++){
            union { uint4 u; f16x2 h[4]; } v;
            v.u = Wr4[(size_t)kg*600 + t];
            a0=fdot2a(v.h[0],uu[kg*4+0],a0);
            a1=fdot2a(v.h[1],uu[kg*4+1],a1);
            a2=fdot2a(v.h[2],uu[kg*4+2],a2);
            a3=fdot2a(v.h[3],uu[kg*4+3],a3);
          }
          partM[t] = (a0+a1)+(a2+a3);
        }
      }
    }
    __syncthreads();
    if (tid < HID){
      float m = partM[2*tid]+partM[2*tid+1];
      Mf[tid]=m; ((_Float16*)Mh)[tid]=(_Float16)m;
    }
    __syncthreads();
    // D: own gates slice -> LDS + LLC exchange; relaxed-only sync
    {
      float* xb = xb0 + (size_t)(i&1)*1824;
      if (tid < 450){
        const int r = 450*sl + tid;
        float a0=0,a1=0,a2=0,a3=0;
        for (int kg=0;kg<38;kg++){
          union { uint4 u; f16x2 h[4]; } v;
          v.u = Wm4[(size_t)kg*1800 + r];
          a0=fdot2a(v.h[0],Mh[kg*4+0],a0);
          a1=fdot2a(v.h[1],Mh[kg*4+1],a1);
          a2=fdot2a(v.h[2],Mh[kg*4+2],a2);
          a3=fdot2a(v.h[3],Mh[kg*4+3],a3);
        }
        float g = (a0+a1)+(a2+a3);
        gates[r] = g;
        xstore(xb + r, g);
      }
      // drain this wave's stores to the coherent point, then count
      asm volatile("s_waitcnt vmcnt(0)" ::: "memory");
      __syncthreads();                       // all waves drained
      if (tid == 0){
        __hip_atomic_fetch_add(cnt, 1, __ATOMIC_RELAXED, __HIP_MEMORY_SCOPE_AGENT);
        while (__hip_atomic_load(cnt, __ATOMIC_RELAXED, __HIP_MEMORY_SCOPE_AGENT) < 4*i)
          __builtin_amdgcn_s_sleep(2);
      }
      __syncthreads();
      // pull the other three slices from LLC
      for (int t = tid; t < 1350; t += 512){
        int r = t + ((t >= 450*sl) ? 450 : 0);
        gates[r] = xload(xb + r);
      }
    }
    __syncthreads();
    // E: GRU combine (replicated); slice 0 writes Hout
    if (tid < HID){
      const float M = Mf[tid];
      float r  = sigm(pr0 + gates[tid] + bcr);
      float z  = sigm(pr1 + gates[300+tid] + bcz);
      float n  = tanhf(pr2 + r*(gates[600+tid]+bcn));
      float C  = (1.f-z)*n + z*M;
      float rp = sigm(gates[900+tid]+bpr + pr3);
      float zp = sigm(gates[1200+tid]+bpz + pr4);
      float np = tanhf(gates[1500+tid]+bpn + rp*pr5);
      float P  = (1.f-zp)*np + zp*qv;
      float h  = C + P;
      if (sl==0) HoutB[(size_t)i*HID + tid] = h;
      Hh[i][tid] = (_Float16)h;
      red[tid] = h*wkv;
    }
    __syncthreads();
    // F: kd[i] = wk . H1[i]
    if (tid < 64){
      float s = red[tid]+red[tid+64]+red[tid+128]+red[tid+192]+red[tid+256];
      #pragma unroll
      for (int o=32;o>0;o>>=1) s += __shfl_xor(s,o);
      if (tid==0) kd[i]=s;
    }
  }
}

// ---------------------------------------------------------------------------
// Head with fp16-dot2 GEMMs.
// ---------------------------------------------------------------------------
__global__ __launch_bounds__(256) void head_kernel(
  const float* __restrict__ H0, const float* __restrict__ Hl1,
  const float* __restrict__ Hl2, const float* __restrict__ Hl3,
  const float* __restrict__ Hl4, const float* __restrict__ feat,
  const f16x2* __restrict__ W14, const float* __restrict__ b1,
  const f16x2* __restrict__ W24, const float* __restrict__ b2,
  const float* __restrict__ w3, const float* __restrict__ b3,
  float* __restrict__ out)
{
  const int tid = threadIdx.x;
  const int r0  = blockIdx.x*16;
  __shared__ f16x2 Xh[16*256];
  __shared__ _Float16 h1h[16*304];
  __shared__ float S2[16*304];
  const uint4* W14u = (const uint4*)W14;
  const uint4* W24u = (const uint4*)W24;

  float acc0[16], acc1[16];
  #pragma unroll
  for (int r=0;r<16;r++){ acc0[r]=0.f; acc1[r]=0.f; }
  const int o  = tid;
  const int o2 = tid + 256;
  const bool has2 = (o2 < 300);

  #pragma unroll
  for (int seg=0; seg<7; seg++){
    const float* src = (seg==0)?H0:(seg==1)?Hl1:(seg==2)?Hl2:(seg==3)?Hl3:(seg==4)?Hl4:feat;
    if (seg < 5){
      for (int t=tid; t<16*152; t+=256){
        int r=t/152, p=t-r*152, c=2*p;
        float v0 = (c<300)? src[(size_t)(r0+r)*300 + c] : 0.f;
        float v1 = (c+1<300)? src[(size_t)(r0+r)*300 + c+1] : 0.f;
        f16x2 h; h.x=(_Float16)v0; h.y=(_Float16)v1;
        Xh[r*256+p] = h;
      }
    } else {
      const int cb = (seg-5)*512;
      for (int t=tid; t<16*256; t+=256){
        int r=t>>8, p=t&255;
        float v0 = src[(size_t)(r0+r)*1024 + cb + 2*p];
        float v1 = src[(size_t)(r0+r)*1024 + cb + 2*p+1];
        f16x2 h; h.x=(_Float16)v0; h.y=(_Float16)v1;
        Xh[r*256+p] = h;
      }
    }
    __syncthreads();
    const int kgs = (seg<5)?38:64;
    const int kgo = (seg<5)? seg*38 : 190+(seg-5)*64;
    if (o < 300){
      for (int kg=0; kg<kgs; kg++){
        union { uint4 u; f16x2 h[4]; } a, b;
        a.u = W14u[(size_t)(kgo+kg)*304 + o];
        if (has2) b.u = W14u[(size_t)(kgo+kg)*304 + o2];
        #pragma unroll
        for (int r=0;r<16;r++){
          const f16x2* xp = &Xh[r*256 + kg*4];
          float t0 = fdot2a(a.h[0], xp[0], 0.f);
          t0 = fdot2a(a.h[1], xp[1], t0);
          t0 = fdot2a(a.h[2], xp[2], t0);
          t0 = fdot2a(a.h[3], xp[3], t0);
          acc0[r] += t0;
          if (has2){
            float t1 = fdot2a(b.h[0], xp[0], 0.f);
            t1 = fdot2a(b.h[1], xp[1], t1);
            t1 = fdot2a(b.h[2], xp[2], t1);
            t1 = fdot2a(b.h[3], xp[3], t1);
            acc1[r] += t1;
          }
        }
      }
    }
    __syncthreads();
  }
  if (o < 300){
    float bb = b1[o];
    #pragma unroll
    for (int r=0;r<16;r++) h1h[r*304+o] = (_Float16)fmaxf(acc0[r]+bb, 0.f);
  }
  if (has2){
    float bb = b1[o2];
    #pragma unroll
    for (int r=0;r<16;r++) h1h[r*304+o2] = (_Float16)fmaxf(acc1[r]+bb, 0.f);
  }
  if (tid < 4){
    #pragma unroll
    for (int r=0;r<16;r++) h1h[r*304+300+tid] = (_Float16)0.f;
  }
  __syncthreads();
  #pragma unroll
  for (int r=0;r<16;r++){ acc0[r]=0.f; acc1[r]=0.f; }
  if (o < 300){
    for (int kg=0; kg<38; kg++){
      union { uint4 u; f16x2 h[4]; } a, b;
      a.u = W24u[(size_t)kg*304 + o];
      if (has2) b.u = W24u[(size_t)kg*304 + o2];
      #pragma unroll
      for (int r=0;r<16;r++){
        const f16x2* xp = (const f16x2*)&h1h[r*304] + kg*4;
        float t0 = fdot2a(a.h[0], xp[0], 0.f);
        t0 = fdot2a(a.h[1], xp[1], t0);
        t0 = fdot2a(a.h[2], xp[2], t0);
        t0 = fdot2a(a.h[3], xp[3], t0);
        acc0[r] += t0;
        if (has2){
          float t1 = fdot2a(b.h[0], xp[0], 0.f);
          t1 = fdot2a(b.h[1], xp[1], t1);
          t1 = fdot2a(b.h[2], xp[2], t1);
          t1 = fdot2a(b.h[3], xp[3], t1);
          acc1[r] += t1;
        }
      }
    }
  }
  __syncthreads();
  if (o < 300){
    float bb = b2[o];
    #pragma unroll
    for (int r=0;r<16;r++) S2[r*304+o] = fmaxf(acc0[r]+bb, 0.f);
  }
  if (has2){
    float bb = b2[o2];
    #pragma unroll
    for (int r=0;r<16;r++) S2[r*304+o2] = fmaxf(acc1[r]+bb, 0.f);
  }
  __syncthreads();
  if (tid < 16*7){
    int r = tid/7, c = tid - r*7;
    float s = b3[c];
    const float* wrow = w3 + (size_t)c*HID;
    for (int k=0;k<HID;k++) s += wrow[k]*S2[r*304+k];
    out[(size_t)(r0+r)*7 + c] = s;
  }
}

// ---------------------------------------------------------------------------
extern "C" void kernel_launch(void* const* d_in, const int* in_sizes, int n_in,
                              void* d_out, int out_size, void* d_ws, size_t ws_size,
                              hipStream_t stream)
{
  (void)in_sizes; (void)n_in; (void)out_size; (void)ws_size;
  const float* feat  = (const float*)d_in[0];
  const int*   spk   = (const int*)d_in[1];
  const float* w_in  = (const float*)d_in[2];
  const float* b_in  = (const float*)d_in[3];
  const float* gwq   = (const float*)d_in[4];
  const float* gwk   = (const float*)d_in[5];
  const float* gb    = (const float*)d_in[6];
  const float* wr0   = (const float*)d_in[7];
  const float* wr1   = (const float*)d_in[8];
  const float* wih_c = (const float*)d_in[9];
  const float* whh_c = (const float*)d_in[10];
  const float* bih_c = (const float*)d_in[11];
  const float* bhh_c = (const float*)d_in[12];
  const float* wih_p = (const float*)d_in[13];
  const float* whh_p = (const float*)d_in[14];
  const float* bih_p = (const float*)d_in[15];
  const float* bhh_p = (const float*)d_in[16];
  const float* w1    = (const float*)d_in[17];
  const float* b1    = (const float*)d_in[18];
  const float* w2    = (const float*)d_in[19];
  const float* b2    = (const float*)d_in[20];
  const float* w3    = (const float*)d_in[21];
  const float* b3    = (const float*)d_in[22];
  float* out = (float*)d_out;

  char* ws = (char*)d_ws;
  size_t off = 0;
  auto alloc = [&](size_t bytes)->void*{
    void* p = ws + off;
    off += (bytes + 255) & ~(size_t)255;
    return p;
  };
  f16x2* W_M4 = (f16x2*)alloc((size_t)4*38*1800*4 * sizeof(f16x2));
  f16x2* WrT4 = (f16x2*)alloc((size_t)4*38*600*4  * sizeof(f16x2));
  f16x2* W_14 = (f16x2*)alloc((size_t)318*304*4   * sizeof(f16x2));
  f16x2* W_24 = (f16x2*)alloc((size_t)38*304*4    * sizeof(f16x2));
  float* Hbuf[5];
  for (int i=0;i<5;i++) Hbuf[i] = (float*)alloc((size_t)NROWS*HID*sizeof(float));
  float* pre   = (float*)alloc((size_t)NROWS*1800*sizeof(float));
  float* qd    = (float*)alloc((size_t)NROWS*sizeof(float));
  float* xchg  = (float*)alloc((size_t)64*3648*sizeof(float));
  int*   syncc = (int*)alloc((size_t)4*64*64*sizeof(int));

  {
    const int tot = 4*38*1800*4 + 4*38*600*4;
    convert_kernel<<<(tot+255)/256, 256, 0, stream>>>(whh_c, wih_p, wr0, wr1, W_M4, WrT4);
  }
  {
    const int tot = 318*304*4 + 38*304*4 + 4*64*64;
    convert_head_kernel<<<(tot+255)/256, 256, 0, stream>>>(w1, w2, W_14, W_24, syncc);
  }
  h0_kernel<<<NROWS/16, 256, 0, stream>>>(feat, w_in, b_in, Hbuf[0]);

  for (int l=0;l<4;l++){
    pre_kernel<<<NROWS/16, 256, 0, stream>>>(Hbuf[l], pre, qd,
        wih_c + (size_t)l*900*HID, whh_p + (size_t)l*900*HID,
        bih_c + l*900, bhh_p + l*900, gwq + l*HID);
    scan_kernel<<<256, 512, 0, stream>>>(Hbuf[l], Hbuf[l+1], pre, qd,
        W_M4 + (size_t)l*38*1800*4, WrT4 + (size_t)l*38*600*4,
        bhh_c + l*900, bih_p + l*900, gwk + l*HID, gb, l, spk, xchg, syncc);
  }
  head_kernel<<<NROWS/16, 256, 0, stream>>>(Hbuf[0], Hbuf[1], Hbuf[2], Hbuf[3], Hbuf[4],
      feat, W_14, b1, W_24, b2, w3, b3, out);
}

// Round 6
// 5261.390 us; speedup vs baseline: 1.2471x; 1.2471x over previous
//
#include <hip/hip_runtime.h>
#include <hip/hip_bf16.h>

typedef _Float16 f16x2 __attribute__((ext_vector_type(2)));

#define HID 300
#define NSEQ 64
#define NROWS 4096   // B*N = 64*64

__device__ __forceinline__ float sigm(float x){ return 1.f/(1.f+__expf(-x)); }

__device__ __forceinline__ float fdot2a(f16x2 a, f16x2 b, float c){
#if __has_builtin(__builtin_amdgcn_fdot2)
  return __builtin_amdgcn_fdot2(a, b, c, false);
#else
  return c + (float)a.x*(float)b.x + (float)a.y*(float)b.y;
#endif
}

// ---------------------------------------------------------------------------
// One merged repack kernel: f32 -> fp16 pairs, [kg][outs][4 pairs] coalesced.
//  W_M4 [4][38][1800][4] : rows 0..899 = whh_c, 900..1799 = wih_p   (scan D)
//  WrT4 [4][38][600][4]  : row t=d*2+hh (hh=0 wr0 row d, hh=1 wr1)  (scan C)
//  W_P4 [4][38][1800][4] : rows 0..899 = wih_c, 900..1799 = whh_p   (pre)
//  W_H4 [128][300][4]    : w_in (300x1024)                          (h0)
//  W_14 [318][304][4]    : w1 segments (5x300 Hcat + 2x512 feat)    (head)
//  W_24 [38][304][4]     : w2                                       (head)
// ---------------------------------------------------------------------------
__global__ void convert_all_kernel(
    const float* __restrict__ whh_c, const float* __restrict__ wih_p,
    const float* __restrict__ wih_c, const float* __restrict__ whh_p,
    const float* __restrict__ wr0,   const float* __restrict__ wr1,
    const float* __restrict__ w_in,  const float* __restrict__ w1,
    const float* __restrict__ w2,
    f16x2* __restrict__ W_M4, f16x2* __restrict__ WrT4, f16x2* __restrict__ W_P4,
    f16x2* __restrict__ W_H4, f16x2* __restrict__ W_14, f16x2* __restrict__ W_24)
{
  const int NA = 4*38*1800*4;
  const int NB = 4*38*600*4;
  const int NP = 4*38*1800*4;
  const int NH = 128*300*4;
  const int N1 = 318*304*4;
  const int N2 = 38*304*4;
  const int TOT = NA+NB+NP+NH+N1+N2;
  for (int idx0 = blockIdx.x*blockDim.x + threadIdx.x; idx0 < TOT; idx0 += gridDim.x*blockDim.x){
    int idx = idx0;
    if (idx < NA){
      int l    = idx/(38*1800*4);
      int rem  = idx - l*(38*1800*4);
      int kg   = rem/(1800*4);
      int rem2 = rem - kg*(1800*4);
      int o = rem2>>2, s = rem2&3;
      int c = (kg*4+s)*2;
      float v0=0.f, v1=0.f;
      if (c < 300){
        const float* src = (o<900) ? (whh_c + ((size_t)l*900+o)*300)
                                   : (wih_p + ((size_t)l*900+(o-900))*300);
        v0 = src[c]; v1 = src[c+1];
      }
      f16x2 t; t.x=(_Float16)v0; t.y=(_Float16)v1;
      W_M4[idx] = t; continue;
    }
    idx -= NA;
    if (idx < NB){
      int l    = idx/(38*600*4);
      int rem  = idx - l*(38*600*4);
      int kg   = rem/(600*4);
      int rem2 = rem - kg*(600*4);
      int t6 = rem2>>2, s = rem2&3;
      int d = t6>>1, hh = t6&1;
      int c = (kg*4+s)*2;
      float v0=0.f, v1=0.f;
      if (c < 300){
        const float* src = hh ? (wr1 + ((size_t)l*300+d)*300)
                              : (wr0 + ((size_t)l*300+d)*300);
        v0 = src[c]; v1 = src[c+1];
      }
      f16x2 t; t.x=(_Float16)v0; t.y=(_Float16)v1;
      WrT4[idx] = t; continue;
    }
    idx -= NB;
    if (idx < NP){
      int l    = idx/(38*1800*4);
      int rem  = idx - l*(38*1800*4);
      int kg   = rem/(1800*4);
      int rem2 = rem - kg*(1800*4);
      int o = rem2>>2, s = rem2&3;
      int c = (kg*4+s)*2;
      float v0=0.f, v1=0.f;
      if (c < 300){
        const float* src = (o<900) ? (wih_c + ((size_t)l*900+o)*300)
                                   : (whh_p + ((size_t)l*900+(o-900))*300);
        v0 = src[c]; v1 = src[c+1];
      }
      f16x2 t; t.x=(_Float16)v0; t.y=(_Float16)v1;
      W_P4[idx] = t; continue;
    }
    idx -= NP;
    if (idx < NH){
      int kg  = idx/(300*4);
      int rem = idx - kg*(300*4);
      int o = rem>>2, s = rem&3;
      int c = (kg*4+s)*2;   // < 1024 always (128*4*2 = 1024)
      f16x2 t; t.x=(_Float16)w_in[(size_t)o*1024+c]; t.y=(_Float16)w_in[(size_t)o*1024+c+1];
      W_H4[idx] = t; continue;
    }
    idx -= NH;
    if (idx < N1){
      int kgg = idx/(304*4);
      int rem = idx - kgg*(304*4);
      int o = rem>>2, s = rem&3;
      int segbase, seglen, kgl;
      if (kgg < 190){ int seg = kgg/38; kgl = kgg - seg*38; segbase = seg*300; seglen = 300; }
      else { int kk = kgg-190; int sf = kk>>6; kgl = kk&63; segbase = 1500 + sf*512; seglen = 512; }
      int c = (kgl*4+s)*2;
      float v0=0.f, v1=0.f;
      if (o < 300 && c < seglen){
        v0 = w1[(size_t)o*2524 + segbase + c];
        if (c+1 < seglen) v1 = w1[(size_t)o*2524 + segbase + c + 1];
      }
      f16x2 t; t.x=(_Float16)v0; t.y=(_Float16)v1;
      W_14[idx] = t; continue;
    }
    idx -= N1;
    {
      int kg = idx/(304*4);
      int rem = idx - kg*(304*4);
      int o = rem>>2, s = rem&3;
      int c = (kg*4+s)*2;
      float v0=0.f, v1=0.f;
      if (o < 300 && c < 300){ v0 = w2[(size_t)o*300+c]; v1 = w2[(size_t)o*300+c+1]; }
      f16x2 t; t.x=(_Float16)v0; t.y=(_Float16)v1;
      W_24[idx] = t;
    }
  }
}

// ---------------------------------------------------------------------------
// H0 = relu(features @ w_in^T + b_in), coalesced fp16 weights.
// 8 rows/WG, 512 WGs, 256 thr; thread handles outs {tid, tid+256}.
// ---------------------------------------------------------------------------
__global__ __launch_bounds__(256) void h0_kernel(const float* __restrict__ feat,
    const f16x2* __restrict__ WH, const float* __restrict__ b_in, float* __restrict__ H0)
{
  const int tid = threadIdx.x;
  const int r0  = blockIdx.x*8;
  __shared__ f16x2 X[8][512];
  for (int t=tid; t<8*512; t+=256){
    int r=t>>9, p=t&511, c=2*p;
    f16x2 h; h.x=(_Float16)feat[(size_t)(r0+r)*1024+c];
    h.y=(_Float16)feat[(size_t)(r0+r)*1024+c+1];
    X[r][p]=h;
  }
  __syncthreads();
  const uint4* WHu = (const uint4*)WH;
  const int o0 = tid, o1 = tid+256;
  const bool h1v = (o1 < 300);
  float acc[2][8];
  #pragma unroll
  for (int j=0;j<2;j++)
    #pragma unroll
    for (int r=0;r<8;r++) acc[j][r]=0.f;
  for (int kg=0; kg<128; kg++){
    union { uint4 u; f16x2 h[4]; } w0, w1;
    w0.u = WHu[(size_t)kg*300 + o0];
    if (h1v) w1.u = WHu[(size_t)kg*300 + o1];
    #pragma unroll
    for (int r=0;r<8;r++){
      const f16x2* xp = &X[r][kg*4];
      f16x2 x0=xp[0],x1=xp[1],x2=xp[2],x3=xp[3];
      acc[0][r] = fdot2a(w0.h[3],x3, fdot2a(w0.h[2],x2, fdot2a(w0.h[1],x1, fdot2a(w0.h[0],x0, acc[0][r]))));
      if (h1v)
        acc[1][r] = fdot2a(w1.h[3],x3, fdot2a(w1.h[2],x2, fdot2a(w1.h[1],x1, fdot2a(w1.h[0],x0, acc[1][r]))));
    }
  }
  {
    float bb = b_in[o0];
    #pragma unroll
    for (int r=0;r<8;r++) H0[(size_t)(r0+r)*HID + o0] = fmaxf(acc[0][r]+bb, 0.f);
  }
  if (h1v){
    float bb = b_in[o1];
    #pragma unroll
    for (int r=0;r<8;r++) H0[(size_t)(r0+r)*HID + o1] = fmaxf(acc[1][r]+bb, 0.f);
  }
}

// ---------------------------------------------------------------------------
// Per-layer precompute with coalesced fp16 weights (W_P4).
// pre[row][0..899]=wih_c@Hin+bih_c, [900..1799]=whh_p@Hin+bhh_p, qd=wq.Hin
// 8 rows/WG, 512 WGs, 256 thr; thread handles outs {tid+256j, j=0..6} + tail.
// ---------------------------------------------------------------------------
__global__ __launch_bounds__(256) void pre_kernel(const float* __restrict__ Hin,
    float* __restrict__ pre, float* __restrict__ qd,
    const f16x2* __restrict__ WP, const float* __restrict__ bih_c,
    const float* __restrict__ bhh_p, const float* __restrict__ wq)
{
  const int tid = threadIdx.x;
  const int r0  = blockIdx.x*8;
  __shared__ f16x2 X[8][152];
  for (int t=tid; t<8*152; t+=256){
    int r=t/152, p=t-r*152, c=2*p;
    float v0 = (c<300)? Hin[(size_t)(r0+r)*300+c] : 0.f;
    float v1 = (c+1<300)? Hin[(size_t)(r0+r)*300+c+1] : 0.f;
    f16x2 h; h.x=(_Float16)v0; h.y=(_Float16)v1;
    X[r][p]=h;
  }
  __syncthreads();
  if (tid<8){
    float s=0.f;
    const float* x = Hin + (size_t)(r0+tid)*300;
    for(int k=0;k<300;k++) s += wq[k]*x[k];
    qd[r0+tid]=s;
  }
  const uint4* WPu = (const uint4*)WP;
  int oo[8]; bool vv[8]; float bias[8];
  #pragma unroll
  for (int j=0;j<8;j++){
    int o = (j<7) ? (tid + 256*j) : (1792 + ((tid<8)?tid:0));
    vv[j] = (j<7) || (tid<8);
    oo[j] = o;
    bias[j] = (o<900) ? bih_c[o] : bhh_p[o-900];
  }
  float acc[8][8];
  #pragma unroll
  for (int j=0;j<8;j++)
    #pragma unroll
    for (int r=0;r<8;r++) acc[j][r]=0.f;
  for (int kg=0; kg<38; kg++){
    union { uint4 u; f16x2 h[4]; } w[8];
    #pragma unroll
    for (int j=0;j<8;j++) w[j].u = WPu[(size_t)kg*1800 + oo[j]];
    #pragma unroll
    for (int r=0;r<8;r++){
      const f16x2* xp = &X[r][kg*4];
      f16x2 x0=xp[0],x1=xp[1],x2=xp[2],x3=xp[3];
      #pragma unroll
      for (int j=0;j<8;j++)
        acc[j][r] = fdot2a(w[j].h[3],x3, fdot2a(w[j].h[2],x2, fdot2a(w[j].h[1],x1, fdot2a(w[j].h[0],x0, acc[j][r]))));
    }
  }
  #pragma unroll
  for (int j=0;j<8;j++)
    if (vv[j])
      for (int r=0;r<8;r++)
        pre[(size_t)(r0+r)*1800 + oo[j]] = acc[j][r] + bias[j];
}

// ---------------------------------------------------------------------------
// Sequential scan: one WG per chain (64 WGs x 1024 thr), 63 steps.
// Step-invariant weights for C kg0-1 / D kg0-3 held in registers all 63 steps.
// ---------------------------------------------------------------------------
__global__ __launch_bounds__(1024) void scan_kernel(
  const float* __restrict__ Hin, float* __restrict__ Hout,
  const float* __restrict__ pre, const float* __restrict__ qd,
  const f16x2* __restrict__ Wm, const f16x2* __restrict__ Wrt,
  const float* __restrict__ bhh_c, const float* __restrict__ bih_p,
  const float* __restrict__ wk, const float* __restrict__ gat_b, int layer,
  const int* __restrict__ speakers)
{
  __shared__ _Float16 Hh[NSEQ][304];
  __shared__ float gates[1800];
  __shared__ float Mf[HID];
  __shared__ f16x2 Mh[152];
  __shared__ f16x2 u01h[304];
  __shared__ float partM[600];
  __shared__ float wgt[NSEQ];
  __shared__ float kd[NSEQ];
  __shared__ float qs[NSEQ];
  __shared__ float red[320];
  __shared__ int   spk[NSEQ];
  __shared__ int   startA[NSEQ];

  const int tid = threadIdx.x;
  const int b   = blockIdx.x;
  const int base = b*NSEQ;
  const float* preB = pre + (size_t)base*1800;
  const float* HinB = Hin + (size_t)base*HID;
  float* HoutB      = Hout + (size_t)base*HID;
  const uint4* Wm4  = (const uint4*)Wm;
  const uint4* Wr4  = (const uint4*)Wrt;
  const float gb = gat_b[layer];

  union U { uint4 u; f16x2 h[4]; };
  // persistent (step-invariant) weight registers
  const int o1 = tid, o2 = tid + 1024;
  const bool has2 = (o2 < 1800);
  U pd0[4], pd1[4], pc[2];
  #pragma unroll
  for (int q=0;q<4;q++){
    pd0[q].u = Wm4[(size_t)q*1800 + o1];
    pd1[q].u = has2 ? Wm4[(size_t)q*1800 + o2] : uint4{0,0,0,0};
  }
  if (tid < 600){ pc[0].u = Wr4[tid]; pc[1].u = Wr4[600 + tid]; }
  else { pc[0].u = uint4{0,0,0,0}; pc[1].u = uint4{0,0,0,0}; }

  float bcr=0,bcz=0,bcn=0,bpr=0,bpz=0,bpn=0,wkv=0;
  if (tid < HID){
    bcr=bhh_c[tid]; bcz=bhh_c[300+tid]; bcn=bhh_c[600+tid];
    bpr=bih_p[tid]; bpz=bih_p[300+tid]; bpn=bih_p[600+tid];
    wkv=wk[tid];
  }
  if (tid < NSEQ){ spk[tid] = speakers[base+tid]; qs[tid] = qd[base+tid]; }
  if (tid >= 300 && tid < 320) red[tid] = 0.f;
  if (tid >= 300 && tid < 304){
    ((_Float16*)Mh)[tid]        = (_Float16)0.f;
    ((_Float16*)u01h)[tid]      = (_Float16)0.f;
    ((_Float16*)u01h)[304+tid]  = (_Float16)0.f;
  }
  __syncthreads();
  if (tid < NSEQ){
    int s = 0;
    for (int j=tid-1; j>=0; --j) if (spk[j]==spk[tid]){ s=j; break; }
    startA[tid] = s;
  }
  // i = 0 : C0 = GRU(x0, 0), P0 = GRU(0, x0)
  if (tid < HID){
    const float* p0 = preB;
    float r  = sigm(p0[tid] + bcr);
    float z  = sigm(p0[300+tid] + bcz);
    float n  = tanhf(p0[600+tid] + r*bcn);
    float C0 = (1.f-z)*n;
    float rp = sigm(bpr + p0[900+tid]);
    float zp = sigm(bpz + p0[1200+tid]);
    float np = tanhf(bpn + rp*p0[1500+tid]);
    float x0 = HinB[tid];
    float P0 = (1.f-zp)*np + zp*x0;
    float h  = C0 + P0;
    HoutB[tid] = h;
    Hh[0][tid] = (_Float16)h;
    red[tid]   = h*wkv;
  }
  __syncthreads();
  if (tid < 64){
    float s = red[tid]+red[tid+64]+red[tid+128]+red[tid+192]+red[tid+256];
    #pragma unroll
    for (int o=32;o>0;o>>=1) s += __shfl_xor(s,o);
    if (tid==0) kd[0]=s;
  }

  for (int i=1; i<NSEQ; ++i){
    // prefetch pre row i + Hin row i (consumed only in GRU phase E)
    float pr0=0,pr1=0,pr2=0,pr3=0,pr4=0,pr5=0,qv=0;
    if (tid < HID){
      const float* p = preB + (size_t)i*1800;
      pr0=p[tid]; pr1=p[300+tid]; pr2=p[600+tid];
      pr3=p[900+tid]; pr4=p[1200+tid]; pr5=p[1500+tid];
      qv = HinB[(size_t)i*HID + tid];
    }
    __syncthreads();
    // A: masked softmax over window [startA[i], i-1] (one wave)
    if (tid < 64){
      const int st = startA[i];
      const bool in = (tid>=st) && (tid<i);
      const float q = qs[i];
      float a = in ? (q + kd[tid] + gb) : -3.0e38f;
      float m = a;
      #pragma unroll
      for (int o=32;o>0;o>>=1) m = fmaxf(m, __shfl_xor(m,o));
      float e = in ? __expf(a-m) : 0.f;
      float ssum = e;
      #pragma unroll
      for (int o=32;o>0;o>>=1) ssum += __shfl_xor(ssum,o);
      wgt[tid] = e/ssum;
    }
    __syncthreads();
    // B: u0 = same-speaker weighted sum, u1 = other-speaker
    if (tid < 600){
      const int d  = (tid<300)? tid : (tid-300);
      const int wh = (tid>=300);
      const int st = startA[i]; const int ms = spk[i];
      float u=0.f;
      for (int j=st;j<i;++j){
        float sel = ((spk[j]==ms) != (wh!=0)) ? 1.f : 0.f;
        u += sel*wgt[j]*(float)Hh[j][d];
      }
      ((_Float16*)u01h)[(wh?304:0) + d] = (_Float16)u;
    }
    __syncthreads();
    // C: M = wr0@u0 + wr1@u1 (600 rows; kg0-1 from registers)
    if (tid < 600){
      const int hh = tid&1;
      const f16x2* uu = (const f16x2*)u01h + hh*152;
      float a0,a1,a2,a3;
      a0 = fdot2a(pc[0].h[0], uu[0], 0.f);
      a1 = fdot2a(pc[0].h[1], uu[1], 0.f);
      a2 = fdot2a(pc[0].h[2], uu[2], 0.f);
      a3 = fdot2a(pc[0].h[3], uu[3], 0.f);
      a0 = fdot2a(pc[1].h[0], uu[4], a0);
      a1 = fdot2a(pc[1].h[1], uu[5], a1);
      a2 = fdot2a(pc[1].h[2], uu[6], a2);
      a3 = fdot2a(pc[1].h[3], uu[7], a3);
      for (int kg=2;kg<38;kg++){
        U v; v.u = Wr4[(size_t)kg*600 + tid];
        a0=fdot2a(v.h[0],uu[kg*4+0],a0);
        a1=fdot2a(v.h[1],uu[kg*4+1],a1);
        a2=fdot2a(v.h[2],uu[kg*4+2],a2);
        a3=fdot2a(v.h[3],uu[kg*4+3],a3);
      }
      partM[tid] = (a0+a1)+(a2+a3);
    }
    __syncthreads();
    if (tid < HID){
      float m = partM[2*tid]+partM[2*tid+1];
      Mf[tid]=m; ((_Float16*)Mh)[tid]=(_Float16)m;
    }
    __syncthreads();
    // D: gates = [whh_c ; wih_p] @ M (1800 rows; kg0-3 from registers)
    {
      float a0,a1,a2,a3, e0=0,e1=0,e2=0,e3=0;
      a0 = fdot2a(pd0[0].h[0], Mh[0], 0.f);
      a1 = fdot2a(pd0[0].h[1], Mh[1], 0.f);
      a2 = fdot2a(pd0[0].h[2], Mh[2], 0.f);
      a3 = fdot2a(pd0[0].h[3], Mh[3], 0.f);
      #pragma unroll
      for (int q=1;q<4;q++){
        a0=fdot2a(pd0[q].h[0],Mh[q*4+0],a0);
        a1=fdot2a(pd0[q].h[1],Mh[q*4+1],a1);
        a2=fdot2a(pd0[q].h[2],Mh[q*4+2],a2);
        a3=fdot2a(pd0[q].h[3],Mh[q*4+3],a3);
      }
      if (has2){
        #pragma unroll
        for (int q=0;q<4;q++){
          e0=fdot2a(pd1[q].h[0],Mh[q*4+0],e0);
          e1=fdot2a(pd1[q].h[1],Mh[q*4+1],e1);
          e2=fdot2a(pd1[q].h[2],Mh[q*4+2],e2);
          e3=fdot2a(pd1[q].h[3],Mh[q*4+3],e3);
        }
      }
      for (int kg=4;kg<38;kg++){
        U v0, v1;
        v0.u = Wm4[(size_t)kg*1800 + o1];
        if (has2) v1.u = Wm4[(size_t)kg*1800 + o2];
        f16x2 m0=Mh[kg*4+0], m1=Mh[kg*4+1], m2=Mh[kg*4+2], m3=Mh[kg*4+3];
        a0=fdot2a(v0.h[0],m0,a0); a1=fdot2a(v0.h[1],m1,a1);
        a2=fdot2a(v0.h[2],m2,a2); a3=fdot2a(v0.h[3],m3,a3);
        if (has2){
          e0=fdot2a(v1.h[0],m0,e0); e1=fdot2a(v1.h[1],m1,e1);
          e2=fdot2a(v1.h[2],m2,e2); e3=fdot2a(v1.h[3],m3,e3);
        }
      }
      gates[o1] = (a0+a1)+(a2+a3);
      if (has2) gates[o2] = (e0+e1)+(e2+e3);
    }
    __syncthreads();
    // E: GRU combine, H1[i] = C + P
    if (tid < HID){
      const float M = Mf[tid];
      float r  = sigm(pr0 + gates[tid] + bcr);
      float z  = sigm(pr1 + gates[300+tid] + bcz);
      float n  = tanhf(pr2 + r*(gates[600+tid]+bcn));
      float C  = (1.f-z)*n + z*M;
      float rp = sigm(gates[900+tid]+bpr + pr3);
      float zp = sigm(gates[1200+tid]+bpz + pr4);
      float np = tanhf(gates[1500+tid]+bpn + rp*pr5);
      float P  = (1.f-zp)*np + zp*qv;
      float h  = C + P;
      HoutB[(size_t)i*HID + tid] = h;
      Hh[i][tid] = (_Float16)h;
      red[tid] = h*wkv;
    }
    __syncthreads();
    // F: kd[i] = wk . H1[i]
    if (tid < 64){
      float s = red[tid]+red[tid+64]+red[tid+128]+red[tid+192]+red[tid+256];
      #pragma unroll
      for (int o=32;o>0;o>>=1) s += __shfl_xor(s,o);
      if (tid==0) kd[i]=s;
    }
  }
}

// ---------------------------------------------------------------------------
// Head with fp16-dot2 GEMMs (unchanged from round 5).
// ---------------------------------------------------------------------------
__global__ __launch_bounds__(256) void head_kernel(
  const float* __restrict__ H0, const float* __restrict__ Hl1,
  const float* __restrict__ Hl2, const float* __restrict__ Hl3,
  const float* __restrict__ Hl4, const float* __restrict__ feat,
  const f16x2* __restrict__ W14, const float* __restrict__ b1,
  const f16x2* __restrict__ W24, const float* __restrict__ b2,
  const float* __restrict__ w3, const float* __restrict__ b3,
  float* __restrict__ out)
{
  const int tid = threadIdx.x;
  const int r0  = blockIdx.x*16;
  __shared__ f16x2 Xh[16*256];
  __shared__ _Float16 h1h[16*304];
  __shared__ float S2[16*304];
  const uint4* W14u = (const uint4*)W14;
  const uint4* W24u = (const uint4*)W24;

  float acc0[16], acc1[16];
  #pragma unroll
  for (int r=0;r<16;r++){ acc0[r]=0.f; acc1[r]=0.f; }
  const int o  = tid;
  const int o2 = tid + 256;
  const bool has2 = (o2 < 300);

  #pragma unroll
  for (int seg=0; seg<7; seg++){
    const float* src = (seg==0)?H0:(seg==1)?Hl1:(seg==2)?Hl2:(seg==3)?Hl3:(seg==4)?Hl4:feat;
    if (seg < 5){
      for (int t=tid; t<16*152; t+=256){
        int r=t/152, p=t-r*152, c=2*p;
        float v0 = (c<300)? src[(size_t)(r0+r)*300 + c] : 0.f;
        float v1 = (c+1<300)? src[(size_t)(r0+r)*300 + c+1] : 0.f;
        f16x2 h; h.x=(_Float16)v0; h.y=(_Float16)v1;
        Xh[r*256+p] = h;
      }
    } else {
      const int cb = (seg-5)*512;
      for (int t=tid; t<16*256; t+=256){
        int r=t>>8, p=t&255;
        float v0 = src[(size_t)(r0+r)*1024 + cb + 2*p];
        float v1 = src[(size_t)(r0+r)*1024 + cb + 2*p+1];
        f16x2 h; h.x=(_Float16)v0; h.y=(_Float16)v1;
        Xh[r*256+p] = h;
      }
    }
    __syncthreads();
    const int kgs = (seg<5)?38:64;
    const int kgo = (seg<5)? seg*38 : 190+(seg-5)*64;
    if (o < 300){
      for (int kg=0; kg<kgs; kg++){
        union { uint4 u; f16x2 h[4]; } a, b;
        a.u = W14u[(size_t)(kgo+kg)*304 + o];
        if (has2) b.u = W14u[(size_t)(kgo+kg)*304 + o2];
        #pragma unroll
        for (int r=0;r<16;r++){
          const f16x2* xp = &Xh[r*256 + kg*4];
          float t0 = fdot2a(a.h[0], xp[0], 0.f);
          t0 = fdot2a(a.h[1], xp[1], t0);
          t0 = fdot2a(a.h[2], xp[2], t0);
          t0 = fdot2a(a.h[3], xp[3], t0);
          acc0[r] += t0;
          if (has2){
            float t1 = fdot2a(b.h[0], xp[0], 0.f);
            t1 = fdot2a(b.h[1], xp[1], t1);
            t1 = fdot2a(b.h[2], xp[2], t1);
            t1 = fdot2a(b.h[3], xp[3], t1);
            acc1[r] += t1;
          }
        }
      }
    }
    __syncthreads();
  }
  if (o < 300){
    float bb = b1[o];
    #pragma unroll
    for (int r=0;r<16;r++) h1h[r*304+o] = (_Float16)fmaxf(acc0[r]+bb, 0.f);
  }
  if (has2){
    float bb = b1[o2];
    #pragma unroll
    for (int r=0;r<16;r++) h1h[r*304+o2] = (_Float16)fmaxf(acc1[r]+bb, 0.f);
  }
  if (tid < 4){
    #pragma unroll
    for (int r=0;r<16;r++) h1h[r*304+300+tid] = (_Float16)0.f;
  }
  __syncthreads();
  #pragma unroll
  for (int r=0;r<16;r++){ acc0[r]=0.f; acc1[r]=0.f; }
  if (o < 300){
    for (int kg=0; kg<38; kg++){
      union { uint4 u; f16x2 h[4]; } a, b;
      a.u = W24u[(size_t)kg*304 + o];
      if (has2) b.u = W24u[(size_t)kg*304 + o2];
      #pragma unroll
      for (int r=0;r<16;r++){
        const f16x2* xp = (const f16x2*)&h1h[r*304] + kg*4;
        float t0 = fdot2a(a.h[0], xp[0], 0.f);
        t0 = fdot2a(a.h[1], xp[1], t0);
        t0 = fdot2a(a.h[2], xp[2], t0);
        t0 = fdot2a(a.h[3], xp[3], t0);
        acc0[r] += t0;
        if (has2){
          float t1 = fdot2a(b.h[0], xp[0], 0.f);
          t1 = fdot2a(b.h[1], xp[1], t1);
          t1 = fdot2a(b.h[2], xp[2], t1);
          t1 = fdot2a(b.h[3], xp[3], t1);
          acc1[r] += t1;
        }
      }
    }
  }
  __syncthreads();
  if (o < 300){
    float bb = b2[o];
    #pragma unroll
    for (int r=0;r<16;r++) S2[r*304+o] = fmaxf(acc0[r]+bb, 0.f);
  }
  if (has2){
    float bb = b2[o2];
    #pragma unroll
    for (int r=0;r<16;r++) S2[r*304+o2] = fmaxf(acc1[r]+bb, 0.f);
  }
  __syncthreads();
  if (tid < 16*7){
    int r = tid/7, c = tid - r*7;
    float s = b3[c];
    const float* wrow = w3 + (size_t)c*HID;
    for (int k=0;k<HID;k++) s += wrow[k]*S2[r*304+k];
    out[(size_t)(r0+r)*7 + c] = s;
  }
}

// ---------------------------------------------------------------------------
extern "C" void kernel_launch(void* const* d_in, const int* in_sizes, int n_in,
                              void* d_out, int out_size, void* d_ws, size_t ws_size,
                              hipStream_t stream)
{
  (void)in_sizes; (void)n_in; (void)out_size; (void)ws_size;
  const float* feat  = (const float*)d_in[0];
  const int*   spk   = (const int*)d_in[1];
  const float* w_in  = (const float*)d_in[2];
  const float* b_in  = (const float*)d_in[3];
  const float* gwq   = (const float*)d_in[4];
  const float* gwk   = (const float*)d_in[5];
  const float* gb    = (const float*)d_in[6];
  const float* wr0   = (const float*)d_in[7];
  const float* wr1   = (const float*)d_in[8];
  const float* wih_c = (const float*)d_in[9];
  const float* whh_c = (const float*)d_in[10];
  const float* bih_c = (const float*)d_in[11];
  const float* bhh_c = (const float*)d_in[12];
  const float* wih_p = (const float*)d_in[13];
  const float* whh_p = (const float*)d_in[14];
  const float* bih_p = (const float*)d_in[15];
  const float* bhh_p = (const float*)d_in[16];
  const float* w1    = (const float*)d_in[17];
  const float* b1    = (const float*)d_in[18];
  const float* w2    = (const float*)d_in[19];
  const float* b2    = (const float*)d_in[20];
  const float* w3    = (const float*)d_in[21];
  const float* b3    = (const float*)d_in[22];
  float* out = (float*)d_out;

  char* ws = (char*)d_ws;
  size_t off = 0;
  auto alloc = [&](size_t bytes)->void*{
    void* p = ws + off;
    off += (bytes + 255) & ~(size_t)255;
    return p;
  };
  f16x2* W_M4 = (f16x2*)alloc((size_t)4*38*1800*4 * sizeof(f16x2));
  f16x2* WrT4 = (f16x2*)alloc((size_t)4*38*600*4  * sizeof(f16x2));
  f16x2* W_P4 = (f16x2*)alloc((size_t)4*38*1800*4 * sizeof(f16x2));
  f16x2* W_H4 = (f16x2*)alloc((size_t)128*300*4   * sizeof(f16x2));
  f16x2* W_14 = (f16x2*)alloc((size_t)318*304*4   * sizeof(f16x2));
  f16x2* W_24 = (f16x2*)alloc((size_t)38*304*4    * sizeof(f16x2));
  float* Hbuf[5];
  for (int i=0;i<5;i++) Hbuf[i] = (float*)alloc((size_t)NROWS*HID*sizeof(float));
  float* pre   = (float*)alloc((size_t)NROWS*1800*sizeof(float));
  float* qd    = (float*)alloc((size_t)NROWS*sizeof(float));

  {
    const int tot = 4*38*1800*4 + 4*38*600*4 + 4*38*1800*4 + 128*300*4 + 318*304*4 + 38*304*4;
    int blocks = (tot + 255)/256;
    convert_all_kernel<<<blocks, 256, 0, stream>>>(whh_c, wih_p, wih_c, whh_p,
        wr0, wr1, w_in, w1, w2, W_M4, WrT4, W_P4, W_H4, W_14, W_24);
  }
  h0_kernel<<<NROWS/8, 256, 0, stream>>>(feat, W_H4, b_in, Hbuf[0]);

  for (int l=0;l<4;l++){
    pre_kernel<<<NROWS/8, 256, 0, stream>>>(Hbuf[l], pre, qd,
        W_P4 + (size_t)l*38*1800*4, bih_c + l*900, bhh_p + l*900, gwq + l*HID);
    scan_kernel<<<64, 1024, 0, stream>>>(Hbuf[l], Hbuf[l+1], pre, qd,
        W_M4 + (size_t)l*38*1800*4, WrT4 + (size_t)l*38*600*4,
        bhh_c + l*900, bih_p + l*900, gwk + l*HID, gb, l, spk);
  }
  head_kernel<<<NROWS/16, 256, 0, stream>>>(Hbuf[0], Hbuf[1], Hbuf[2], Hbuf[3], Hbuf[4],
      feat, W_14, b1, W_24, b2, w3, b3, out);
}

// Round 7
// 3435.817 us; speedup vs baseline: 1.9097x; 1.5313x over previous
//
#include <hip/hip_runtime.h>
#include <hip/hip_bf16.h>

typedef _Float16 f16x2 __attribute__((ext_vector_type(2)));

#define HID 300
#define NSEQ 64
#define NROWS 4096   // B*N = 64*64

union U { uint4 u; f16x2 h[4]; };

__device__ __forceinline__ float sigm(float x){ return 1.f/(1.f+__expf(-x)); }

__device__ __forceinline__ float fdot2a(f16x2 a, f16x2 b, float c){
#if __has_builtin(__builtin_amdgcn_fdot2)
  return __builtin_amdgcn_fdot2(a, b, c, false);
#else
  return c + (float)a.x*(float)b.x + (float)a.y*(float)b.y;
#endif
}

// Relaxed agent-scope ops: LLC-coherent, NO cache maintenance (no L2 flush).
__device__ __forceinline__ void xstore(float* p, float v){
  __hip_atomic_store(p, v, __ATOMIC_RELAXED, __HIP_MEMORY_SCOPE_AGENT);
}
__device__ __forceinline__ float xload(const float* p){
  return __hip_atomic_load(p, __ATOMIC_RELAXED, __HIP_MEMORY_SCOPE_AGENT);
}

// ---------------------------------------------------------------------------
// Merged repack: f32 -> fp16 pairs, [kg][outs][4 pairs] coalesced; also zeroes
// the pipeline sync counters every launch (ws is re-poisoned by the harness).
//  W_M4 [4][38][1800][4] : rows 0..899 = whh_c, 900..1799 = wih_p   (scan D)
//  WrT4 [4][38][600][4]  : row t=d*2+hh (hh=0 wr0 row d, hh=1 wr1)  (scan C)
//  W_P4 [4][38][1800][4] : rows 0..899 = wih_c, 900..1799 = whh_p   (fused pre)
//  W_H4 [128][300][4]    : w_in                                     (h0)
//  W_14 [318][304][4]    : w1 segments                              (head)
//  W_24 [38][304][4]     : w2                                       (head)
// ---------------------------------------------------------------------------
__global__ void convert_all_kernel(
    const float* __restrict__ whh_c, const float* __restrict__ wih_p,
    const float* __restrict__ wih_c, const float* __restrict__ whh_p,
    const float* __restrict__ wr0,   const float* __restrict__ wr1,
    const float* __restrict__ w_in,  const float* __restrict__ w1,
    const float* __restrict__ w2,
    f16x2* __restrict__ W_M4, f16x2* __restrict__ WrT4, f16x2* __restrict__ W_P4,
    f16x2* __restrict__ W_H4, f16x2* __restrict__ W_14, f16x2* __restrict__ W_24,
    int* __restrict__ syncc)
{
  const int NA = 4*38*1800*4;
  const int NB = 4*38*600*4;
  const int NP = 4*38*1800*4;
  const int NH = 128*300*4;
  const int N1 = 318*304*4;
  const int N2 = 38*304*4;
  const int NS = 3*64*16;
  const int TOT = NA+NB+NP+NH+N1+N2+NS;
  for (int idx0 = blockIdx.x*blockDim.x + threadIdx.x; idx0 < TOT; idx0 += gridDim.x*blockDim.x){
    int idx = idx0;
    if (idx < NA){
      int l    = idx/(38*1800*4);
      int rem  = idx - l*(38*1800*4);
      int kg   = rem/(1800*4);
      int rem2 = rem - kg*(1800*4);
      int o = rem2>>2, s = rem2&3;
      int c = (kg*4+s)*2;
      float v0=0.f, v1=0.f;
      if (c < 300){
        const float* src = (o<900) ? (whh_c + ((size_t)l*900+o)*300)
                                   : (wih_p + ((size_t)l*900+(o-900))*300);
        v0 = src[c]; v1 = src[c+1];
      }
      f16x2 t; t.x=(_Float16)v0; t.y=(_Float16)v1;
      W_M4[idx] = t; continue;
    }
    idx -= NA;
    if (idx < NB){
      int l    = idx/(38*600*4);
      int rem  = idx - l*(38*600*4);
      int kg   = rem/(600*4);
      int rem2 = rem - kg*(600*4);
      int t6 = rem2>>2, s = rem2&3;
      int d = t6>>1, hh = t6&1;
      int c = (kg*4+s)*2;
      float v0=0.f, v1=0.f;
      if (c < 300){
        const float* src = hh ? (wr1 + ((size_t)l*300+d)*300)
                              : (wr0 + ((size_t)l*300+d)*300);
        v0 = src[c]; v1 = src[c+1];
      }
      f16x2 t; t.x=(_Float16)v0; t.y=(_Float16)v1;
      WrT4[idx] = t; continue;
    }
    idx -= NB;
    if (idx < NP){
      int l    = idx/(38*1800*4);
      int rem  = idx - l*(38*1800*4);
      int kg   = rem/(1800*4);
      int rem2 = rem - kg*(1800*4);
      int o = rem2>>2, s = rem2&3;
      int c = (kg*4+s)*2;
      float v0=0.f, v1=0.f;
      if (c < 300){
        const float* src = (o<900) ? (wih_c + ((size_t)l*900+o)*300)
                                   : (whh_p + ((size_t)l*900+(o-900))*300);
        v0 = src[c]; v1 = src[c+1];
      }
      f16x2 t; t.x=(_Float16)v0; t.y=(_Float16)v1;
      W_P4[idx] = t; continue;
    }
    idx -= NP;
    if (idx < NH){
      int kg  = idx/(300*4);
      int rem = idx - kg*(300*4);
      int o = rem>>2, s = rem&3;
      int c = (kg*4+s)*2;
      f16x2 t; t.x=(_Float16)w_in[(size_t)o*1024+c]; t.y=(_Float16)w_in[(size_t)o*1024+c+1];
      W_H4[idx] = t; continue;
    }
    idx -= NH;
    if (idx < N1){
      int kgg = idx/(304*4);
      int rem = idx - kgg*(304*4);
      int o = rem>>2, s = rem&3;
      int segbase, seglen, kgl;
      if (kgg < 190){ int seg = kgg/38; kgl = kgg - seg*38; segbase = seg*300; seglen = 300; }
      else { int kk = kgg-190; int sf = kk>>6; kgl = kk&63; segbase = 1500 + sf*512; seglen = 512; }
      int c = (kgl*4+s)*2;
      float v0=0.f, v1=0.f;
      if (o < 300 && c < seglen){
        v0 = w1[(size_t)o*2524 + segbase + c];
        if (c+1 < seglen) v1 = w1[(size_t)o*2524 + segbase + c + 1];
      }
      f16x2 t; t.x=(_Float16)v0; t.y=(_Float16)v1;
      W_14[idx] = t; continue;
    }
    idx -= N1;
    if (idx < N2){
      int kg = idx/(304*4);
      int rem = idx - kg*(304*4);
      int o = rem>>2, s = rem&3;
      int c = (kg*4+s)*2;
      float v0=0.f, v1=0.f;
      if (o < 300 && c < 300){ v0 = w2[(size_t)o*300+c]; v1 = w2[(size_t)o*300+c+1]; }
      f16x2 t; t.x=(_Float16)v0; t.y=(_Float16)v1;
      W_24[idx] = t; continue;
    }
    idx -= N2;
    syncc[idx] = 0;
  }
}

// ---------------------------------------------------------------------------
// H0 = relu(features @ w_in^T + b_in), coalesced fp16 weights. (as R6)
// ---------------------------------------------------------------------------
__global__ __launch_bounds__(256) void h0_kernel(const float* __restrict__ feat,
    const f16x2* __restrict__ WH, const float* __restrict__ b_in, float* __restrict__ H0)
{
  const int tid = threadIdx.x;
  const int r0  = blockIdx.x*8;
  __shared__ f16x2 X[8][512];
  for (int t=tid; t<8*512; t+=256){
    int r=t>>9, p=t&511, c=2*p;
    f16x2 h; h.x=(_Float16)feat[(size_t)(r0+r)*1024+c];
    h.y=(_Float16)feat[(size_t)(r0+r)*1024+c+1];
    X[r][p]=h;
  }
  __syncthreads();
  const uint4* WHu = (const uint4*)WH;
  const int o0 = tid, o1 = tid+256;
  const bool h1v = (o1 < 300);
  float acc[2][8];
  #pragma unroll
  for (int j=0;j<2;j++)
    #pragma unroll
    for (int r=0;r<8;r++) acc[j][r]=0.f;
  for (int kg=0; kg<128; kg++){
    U w0, w1;
    w0.u = WHu[(size_t)kg*300 + o0];
    if (h1v) w1.u = WHu[(size_t)kg*300 + o1];
    #pragma unroll
    for (int r=0;r<8;r++){
      const f16x2* xp = &X[r][kg*4];
      f16x2 x0=xp[0],x1=xp[1],x2=xp[2],x3=xp[3];
      acc[0][r] = fdot2a(w0.h[3],x3, fdot2a(w0.h[2],x2, fdot2a(w0.h[1],x1, fdot2a(w0.h[0],x0, acc[0][r]))));
      if (h1v)
        acc[1][r] = fdot2a(w1.h[3],x3, fdot2a(w1.h[2],x2, fdot2a(w1.h[1],x1, fdot2a(w1.h[0],x0, acc[1][r]))));
    }
  }
  {
    float bb = b_in[o0];
    #pragma unroll
    for (int r=0;r<8;r++) H0[(size_t)(r0+r)*HID + o0] = fmaxf(acc[0][r]+bb, 0.f);
  }
  if (h1v){
    float bb = b_in[o1];
    #pragma unroll
    for (int r=0;r<8;r++) H0[(size_t)(r0+r)*HID + o1] = fmaxf(acc[1][r]+bb, 0.f);
  }
}

// ---------------------------------------------------------------------------
// Fused 4-layer pipelined scan. 256 WGs = 64 chains x 4 layers.
// bid%8 = XCD (heuristic): layer = (bid&7)>>1 -> each layer's 64 WGs on 2 XCDs
// so its 2.5 MB weight set stays L2-resident. Layer l+1 consumes layer l's
// H rows one step behind via relaxed LLC atomics + per-(layer,chain) counter.
// pre-GEMV fused (pre_kernel eliminated).
// ---------------------------------------------------------------------------
__global__ __launch_bounds__(1024) void scan_pipe_kernel(
  float* __restrict__ Hball,
  const f16x2* __restrict__ W_M4, const f16x2* __restrict__ WrT4, const f16x2* __restrict__ W_P4,
  const float* __restrict__ bih_c, const float* __restrict__ bhh_c,
  const float* __restrict__ bih_p, const float* __restrict__ bhh_p,
  const float* __restrict__ gwq, const float* __restrict__ gwk, const float* __restrict__ gbv,
  const int* __restrict__ speakers, float* __restrict__ xrow, int* __restrict__ syncc)
{
  __shared__ _Float16 Hh[NSEQ][304];
  __shared__ float pre_s[1800];
  __shared__ float gates[1800];
  __shared__ float Mf[304];
  __shared__ f16x2 Mh[152];
  __shared__ f16x2 u01h[304];
  __shared__ float wgt[NSEQ];
  __shared__ float kd[NSEQ];
  __shared__ float red[320];
  __shared__ float xf[304];
  __shared__ f16x2 xh[152];
  __shared__ int   spk[NSEQ];
  __shared__ int   startA[NSEQ];

  const int tid   = threadIdx.x;
  const int bid   = blockIdx.x;
  const int layer = (bid & 7) >> 1;
  const int chain = ((bid >> 3) << 1) | (bid & 1);
  const int base  = chain * NSEQ;

  const uint4* Wm4 = (const uint4*)(W_M4 + (size_t)layer*38*1800*4);
  const uint4* Wr4 = (const uint4*)(WrT4 + (size_t)layer*38*600*4);
  const uint4* Wp4 = (const uint4*)(W_P4 + (size_t)layer*38*1800*4);
  const float* HinB = Hball + (size_t)base*300;                       // layer 0 input
  float* HoutB = Hball + ((size_t)(layer+1)*NROWS + (size_t)base)*300;
  const float gb = gbv[layer];
  int* cntP = syncc + (layer*64 + chain)*16;
  int* cntC = (layer>0) ? (syncc + ((layer-1)*64 + chain)*16) : (int*)0;
  const float* xin  = xrow + (size_t)((layer-1)*64 + chain)*NSEQ*300; // layer>0
  float*       xout = xrow + (size_t)(layer*64 + chain)*NSEQ*300;     // layer<3

  // step-invariant per-thread regs
  float bcr=0,bcz=0,bcn=0,bpr=0,bpz=0,bpn=0,wkv=0;
  if (tid < 300){
    bcr=bhh_c[layer*900+tid]; bcz=bhh_c[layer*900+300+tid]; bcn=bhh_c[layer*900+600+tid];
    bpr=bih_p[layer*900+tid]; bpz=bih_p[layer*900+300+tid]; bpn=bih_p[layer*900+600+tid];
    wkv=gwk[layer*300+tid];
  }
  float wq0r=0, wq1r=0;
  if (tid < 150){ wq0r = gwq[layer*300+2*tid]; wq1r = gwq[layer*300+2*tid+1]; }
  const int pt  = tid - 64;        // pre-GEMV thread index (waves 1..15)
  const int po1 = pt, po2 = 960 + pt;
  const bool p2v = (pt >= 0) && (pt < 840);
  float pb1=0, pb2=0;
  if (tid >= 64){
    pb1 = (po1<900) ? bih_c[layer*900+po1] : bhh_p[layer*900+po1-900];
    if (p2v) pb2 = bhh_p[layer*900+po2-900];
  }
  const int o1 = tid, o2 = tid+1024;
  const bool dhas2 = (o2 < 1800);

  if (tid < NSEQ) spk[tid] = speakers[base+tid];
  if (tid >= 300 && tid < 320) red[tid]=0.f;
  if (tid >= 300 && tid < 304) xf[tid]=0.f;
  for (int t=tid; t<1800; t+=1024) gates[t]=0.f;
  if (tid < 304) Mf[tid]=0.f;
  if (tid < 2){
    f16x2 z; z.x=(_Float16)0.f; z.y=(_Float16)0.f;
    Mh[150+tid]=z; xh[150+tid]=z; u01h[150+tid]=z; u01h[302+tid]=z;
  }
  __syncthreads();
  if (tid < NSEQ){
    int s=0; for (int j=tid-1;j>=0;--j) if (spk[j]==spk[tid]){s=j;break;}
    startA[tid]=s;
  }
  if (layer>0 && tid==0){
    while (__hip_atomic_load(cntC, __ATOMIC_RELAXED, __HIP_MEMORY_SCOPE_AGENT) < 1)
      __builtin_amdgcn_s_sleep(8);
  }
  __syncthreads();

  for (int i=0; i<NSEQ; ++i){
    // R: receive/load input row i (300 f32) -> xf (f32) + xh (fp16) + qd products
    if (tid < 150){
      float x0, x1;
      if (layer==0){
        float2 v = *(const float2*)(HinB + (size_t)i*300 + 2*tid);
        x0=v.x; x1=v.y;
      } else {
        x0 = xload(xin + (size_t)i*300 + 2*tid);
        x1 = xload(xin + (size_t)i*300 + 2*tid + 1);
      }
      xf[2*tid]=x0; xf[2*tid+1]=x1;
      f16x2 h; h.x=(_Float16)x0; h.y=(_Float16)x1; xh[tid]=h;
      red[tid] = x0*wq0r + x1*wq1r;
    }
    __syncthreads();
    // P: fused pre-GEMV on waves 1..15  ||  A: qd-reduce + softmax on wave 0
    if (tid >= 64){
      float a0=0,a1=0,a2=0,a3=0, e0=0,e1=0,e2=0,e3=0;
      for (int kg=0;kg<38;kg++){
        U v0, v1;
        v0.u = Wp4[(size_t)kg*1800 + po1];
        if (p2v) v1.u = Wp4[(size_t)kg*1800 + po2];
        f16x2 x0=xh[kg*4+0],x1=xh[kg*4+1],x2=xh[kg*4+2],x3=xh[kg*4+3];
        a0=fdot2a(v0.h[0],x0,a0); a1=fdot2a(v0.h[1],x1,a1);
        a2=fdot2a(v0.h[2],x2,a2); a3=fdot2a(v0.h[3],x3,a3);
        if (p2v){ e0=fdot2a(v1.h[0],x0,e0); e1=fdot2a(v1.h[1],x1,e1);
                  e2=fdot2a(v1.h[2],x2,e2); e3=fdot2a(v1.h[3],x3,e3); }
      }
      pre_s[po1] = (a0+a1)+(a2+a3) + pb1;
      if (p2v) pre_s[po2] = (e0+e1)+(e2+e3) + pb2;
    } else if (i > 0){
      float s = red[tid] + red[tid+64] + ((tid<22)? red[tid+128] : 0.f);
      #pragma unroll
      for (int o=32;o>0;o>>=1) s += __shfl_xor(s,o);
      const float q = s;
      const int st = startA[i];
      const bool in = (tid>=st) && (tid<i);
      float a = in ? (q + kd[tid] + gb) : -3.0e38f;
      float m = a;
      #pragma unroll
      for (int o=32;o>0;o>>=1) m = fmaxf(m,__shfl_xor(m,o));
      float e = in ? __expf(a-m) : 0.f;
      float ss = e;
      #pragma unroll
      for (int o=32;o>0;o>>=1) ss += __shfl_xor(ss,o);
      wgt[tid] = e/ss;
    }
    __syncthreads();
    if (i > 0){
      // B: u0 (same-speaker) / u1 (other) weighted history sums
      if (tid < 600){
        const int d  = (tid<300)? tid : (tid-300);
        const int wh = (tid>=300);
        const int st = startA[i]; const int ms = spk[i];
        float u=0.f;
        for (int j=st;j<i;++j){
          float sel = ((spk[j]==ms) != (wh!=0)) ? 1.f : 0.f;
          u += sel*wgt[j]*(float)Hh[j][d];
        }
        ((_Float16*)u01h)[(wh?304:0) + d] = (_Float16)u;
      }
      __syncthreads();
      // C: M = wr0@u0 + wr1@u1 ; pair-combine + Mh pack via in-wave shuffles
      if (tid < 600){
        const int hh = tid&1;
        const f16x2* uu = (const f16x2*)u01h + hh*152;
        float a0=0,a1=0,a2=0,a3=0;
        for (int kg=0;kg<38;kg++){
          U v; v.u = Wr4[(size_t)kg*600 + tid];
          a0=fdot2a(v.h[0],uu[kg*4+0],a0);
          a1=fdot2a(v.h[1],uu[kg*4+1],a1);
          a2=fdot2a(v.h[2],uu[kg*4+2],a2);
          a3=fdot2a(v.h[3],uu[kg*4+3],a3);
        }
        float a = (a0+a1)+(a2+a3);
        float m2 = a + __shfl_xor(a,1);         // M[d], d = tid>>1
        if ((tid&1)==0) Mf[tid>>1] = m2;
        float mo = __shfl_xor(m2,2);            // M[d^1]
        if ((tid&3)==0){ f16x2 mh; mh.x=(_Float16)m2; mh.y=(_Float16)mo; Mh[tid>>2]=mh; }
      }
      __syncthreads();
      // D: gates = [whh_c ; wih_p] @ M (1800 rows, 2/thread)
      {
        float a0=0,a1=0,a2=0,a3=0, e0=0,e1=0,e2=0,e3=0;
        for (int kg=0;kg<38;kg++){
          U v0, v1;
          v0.u = Wm4[(size_t)kg*1800 + o1];
          if (dhas2) v1.u = Wm4[(size_t)kg*1800 + o2];
          f16x2 m0=Mh[kg*4+0], m1=Mh[kg*4+1], m2=Mh[kg*4+2], m3=Mh[kg*4+3];
          a0=fdot2a(v0.h[0],m0,a0); a1=fdot2a(v0.h[1],m1,a1);
          a2=fdot2a(v0.h[2],m2,a2); a3=fdot2a(v0.h[3],m3,a3);
          if (dhas2){ e0=fdot2a(v1.h[0],m0,e0); e1=fdot2a(v1.h[1],m1,e1);
                      e2=fdot2a(v1.h[2],m2,e2); e3=fdot2a(v1.h[3],m3,e3); }
        }
        gates[o1] = (a0+a1)+(a2+a3);
        if (dhas2) gates[o2] = (e0+e1)+(e2+e3);
      }
      __syncthreads();
    }
    // E: GRU combine; write Hout + own history + publish to consumer
    if (tid < 300){
      const float M = Mf[tid];
      float r  = sigm(pre_s[tid] + gates[tid] + bcr);
      float z  = sigm(pre_s[300+tid] + gates[300+tid] + bcz);
      float n  = tanhf(pre_s[600+tid] + r*(gates[600+tid]+bcn));
      float C  = (1.f-z)*n + z*M;
      float rp = sigm(gates[900+tid]+bpr + pre_s[900+tid]);
      float zp = sigm(gates[1200+tid]+bpz + pre_s[1200+tid]);
      float np = tanhf(gates[1500+tid]+bpn + rp*pre_s[1500+tid]);
      float qv = xf[tid];
      float P  = (1.f-zp)*np + zp*qv;
      float h  = C + P;
      HoutB[(size_t)i*300 + tid] = h;
      Hh[i][tid] = (_Float16)h;
      red[tid] = h*wkv;
      if (layer<3) xstore(xout + (size_t)i*300 + tid, h);
    }
    asm volatile("s_waitcnt vmcnt(0)" ::: "memory");   // drain publish before counting
    __syncthreads();
    // F: kd[i]; bump own counter; poll producer for next row
    if (tid < 64){
      float s = red[tid]+red[tid+64]+red[tid+128]+red[tid+192]+red[tid+256];
      #pragma unroll
      for (int o=32;o>0;o>>=1) s += __shfl_xor(s,o);
      if (tid==0) kd[i]=s;
    }
    if (tid==0){
      if (layer<3) __hip_atomic_fetch_add(cntP, 1, __ATOMIC_RELAXED, __HIP_MEMORY_SCOPE_AGENT);
      if (layer>0 && i<63){
        while (__hip_atomic_load(cntC, __ATOMIC_RELAXED, __HIP_MEMORY_SCOPE_AGENT) < i+2)
          __builtin_amdgcn_s_sleep(8);
      }
    }
    __syncthreads();
  }
}

// ---------------------------------------------------------------------------
// Head with fp16-dot2 GEMMs (unchanged).
// ---------------------------------------------------------------------------
__global__ __launch_bounds__(256) void head_kernel(
  const float* __restrict__ H0, const float* __restrict__ Hl1,
  const float* __restrict__ Hl2, const float* __restrict__ Hl3,
  const float* __restrict__ Hl4, const float* __restrict__ feat,
  const f16x2* __restrict__ W14, const float* __restrict__ b1,
  const f16x2* __restrict__ W24, const float* __restrict__ b2,
  const float* __restrict__ w3, const float* __restrict__ b3,
  float* __restrict__ out)
{
  const int tid = threadIdx.x;
  const int r0  = blockIdx.x*16;
  __shared__ f16x2 Xh[16*256];
  __shared__ _Float16 h1h[16*304];
  __shared__ float S2[16*304];
  const uint4* W14u = (const uint4*)W14;
  const uint4* W24u = (const uint4*)W24;

  float acc0[16], acc1[16];
  #pragma unroll
  for (int r=0;r<16;r++){ acc0[r]=0.f; acc1[r]=0.f; }
  const int o  = tid;
  const int o2 = tid + 256;
  const bool has2 = (o2 < 300);

  #pragma unroll
  for (int seg=0; seg<7; seg++){
    const float* src = (seg==0)?H0:(seg==1)?Hl1:(seg==2)?Hl2:(seg==3)?Hl3:(seg==4)?Hl4:feat;
    if (seg < 5){
      for (int t=tid; t<16*152; t+=256){
        int r=t/152, p=t-r*152, c=2*p;
        float v0 = (c<300)? src[(size_t)(r0+r)*300 + c] : 0.f;
        float v1 = (c+1<300)? src[(size_t)(r0+r)*300 + c+1] : 0.f;
        f16x2 h; h.x=(_Float16)v0; h.y=(_Float16)v1;
        Xh[r*256+p] = h;
      }
    } else {
      const int cb = (seg-5)*512;
      for (int t=tid; t<16*256; t+=256){
        int r=t>>8, p=t&255;
        float v0 = src[(size_t)(r0+r)*1024 + cb + 2*p];
        float v1 = src[(size_t)(r0+r)*1024 + cb + 2*p+1];
        f16x2 h; h.x=(_Float16)v0; h.y=(_Float16)v1;
        Xh[r*256+p] = h;
      }
    }
    __syncthreads();
    const int kgs = (seg<5)?38:64;
    const int kgo = (seg<5)? seg*38 : 190+(seg-5)*64;
    if (o < 300){
      for (int kg=0; kg<kgs; kg++){
        U a, b;
        a.u = W14u[(size_t)(kgo+kg)*304 + o];
        if (has2) b.u = W14u[(size_t)(kgo+kg)*304 + o2];
        #pragma unroll
        for (int r=0;r<16;r++){
          const f16x2* xp = &Xh[r*256 + kg*4];
          float t0 = fdot2a(a.h[0], xp[0], 0.f);
          t0 = fdot2a(a.h[1], xp[1], t0);
          t0 = fdot2a(a.h[2], xp[2], t0);
          t0 = fdot2a(a.h[3], xp[3], t0);
          acc0[r] += t0;
          if (has2){
            float t1 = fdot2a(b.h[0], xp[0], 0.f);
            t1 = fdot2a(b.h[1], xp[1], t1);
            t1 = fdot2a(b.h[2], xp[2], t1);
            t1 = fdot2a(b.h[3], xp[3], t1);
            acc1[r] += t1;
          }
        }
      }
    }
    __syncthreads();
  }
  if (o < 300){
    float bb = b1[o];
    #pragma unroll
    for (int r=0;r<16;r++) h1h[r*304+o] = (_Float16)fmaxf(acc0[r]+bb, 0.f);
  }
  if (has2){
    float bb = b1[o2];
    #pragma unroll
    for (int r=0;r<16;r++) h1h[r*304+o2] = (_Float16)fmaxf(acc1[r]+bb, 0.f);
  }
  if (tid < 4){
    #pragma unroll
    for (int r=0;r<16;r++) h1h[r*304+300+tid] = (_Float16)0.f;
  }
  __syncthreads();
  #pragma unroll
  for (int r=0;r<16;r++){ acc0[r]=0.f; acc1[r]=0.f; }
  if (o < 300){
    for (int kg=0; kg<38; kg++){
      U a, b;
      a.u = W24u[(size_t)kg*304 + o];
      if (has2) b.u = W24u[(size_t)kg*304 + o2];
      #pragma unroll
      for (int r=0;r<16;r++){
        const f16x2* xp = (const f16x2*)&h1h[r*304] + kg*4;
        float t0 = fdot2a(a.h[0], xp[0], 0.f);
        t0 = fdot2a(a.h[1], xp[1], t0);
        t0 = fdot2a(a.h[2], xp[2], t0);
        t0 = fdot2a(a.h[3], xp[3], t0);
        acc0[r] += t0;
        if (has2){
          float t1 = fdot2a(b.h[0], xp[0], 0.f);
          t1 = fdot2a(b.h[1], xp[1], t1);
          t1 = fdot2a(b.h[2], xp[2], t1);
          t1 = fdot2a(b.h[3], xp[3], t1);
          acc1[r] += t1;
        }
      }
    }
  }
  __syncthreads();
  if (o < 300){
    float bb = b2[o];
    #pragma unroll
    for (int r=0;r<16;r++) S2[r*304+o] = fmaxf(acc0[r]+bb, 0.f);
  }
  if (has2){
    float bb = b2[o2];
    #pragma unroll
    for (int r=0;r<16;r++) S2[r*304+o2] = fmaxf(acc1[r]+bb, 0.f);
  }
  __syncthreads();
  if (tid < 16*7){
    int r = tid/7, c = tid - r*7;
    float s = b3[c];
    const float* wrow = w3 + (size_t)c*HID;
    for (int k=0;k<HID;k++) s += wrow[k]*S2[r*304+k];
    out[(size_t)(r0+r)*7 + c] = s;
  }
}

// ---------------------------------------------------------------------------
extern "C" void kernel_launch(void* const* d_in, const int* in_sizes, int n_in,
                              void* d_out, int out_size, void* d_ws, size_t ws_size,
                              hipStream_t stream)
{
  (void)in_sizes; (void)n_in; (void)out_size; (void)ws_size;
  const float* feat  = (const float*)d_in[0];
  const int*   spk   = (const int*)d_in[1];
  const float* w_in  = (const float*)d_in[2];
  const float* b_in  = (const float*)d_in[3];
  const float* gwq   = (const float*)d_in[4];
  const float* gwk   = (const float*)d_in[5];
  const float* gb    = (const float*)d_in[6];
  const float* wr0   = (const float*)d_in[7];
  const float* wr1   = (const float*)d_in[8];
  const float* wih_c = (const float*)d_in[9];
  const float* whh_c = (const float*)d_in[10];
  const float* bih_c = (const float*)d_in[11];
  const float* bhh_c = (const float*)d_in[12];
  const float* wih_p = (const float*)d_in[13];
  const float* whh_p = (const float*)d_in[14];
  const float* bih_p = (const float*)d_in[15];
  const float* bhh_p = (const float*)d_in[16];
  const float* w1    = (const float*)d_in[17];
  const float* b1    = (const float*)d_in[18];
  const float* w2    = (const float*)d_in[19];
  const float* b2    = (const float*)d_in[20];
  const float* w3    = (const float*)d_in[21];
  const float* b3    = (const float*)d_in[22];
  float* out = (float*)d_out;

  char* ws = (char*)d_ws;
  size_t off = 0;
  auto alloc = [&](size_t bytes)->void*{
    void* p = ws + off;
    off += (bytes + 255) & ~(size_t)255;
    return p;
  };
  f16x2* W_M4 = (f16x2*)alloc((size_t)4*38*1800*4 * sizeof(f16x2));
  f16x2* WrT4 = (f16x2*)alloc((size_t)4*38*600*4  * sizeof(f16x2));
  f16x2* W_P4 = (f16x2*)alloc((size_t)4*38*1800*4 * sizeof(f16x2));
  f16x2* W_H4 = (f16x2*)alloc((size_t)128*300*4   * sizeof(f16x2));
  f16x2* W_14 = (f16x2*)alloc((size_t)318*304*4   * sizeof(f16x2));
  f16x2* W_24 = (f16x2*)alloc((size_t)38*304*4    * sizeof(f16x2));
  float* Hball = (float*)alloc((size_t)5*NROWS*HID*sizeof(float));
  float* xrow  = (float*)alloc((size_t)3*64*NSEQ*HID*sizeof(float));
  int*   syncc = (int*)alloc((size_t)3*64*16*sizeof(int));

  {
    const int tot = 4*38*1800*4 + 4*38*600*4 + 4*38*1800*4 + 128*300*4
                  + 318*304*4 + 38*304*4 + 3*64*16;
    convert_all_kernel<<<(tot+255)/256, 256, 0, stream>>>(whh_c, wih_p, wih_c, whh_p,
        wr0, wr1, w_in, w1, w2, W_M4, WrT4, W_P4, W_H4, W_14, W_24, syncc);
  }
  h0_kernel<<<NROWS/8, 256, 0, stream>>>(feat, W_H4, b_in, Hball);

  scan_pipe_kernel<<<256, 1024, 0, stream>>>(Hball, W_M4, WrT4, W_P4,
      bih_c, bhh_c, bih_p, bhh_p, gwq, gwk, gb, spk, xrow, syncc);

  head_kernel<<<NROWS/16, 256, 0, stream>>>(
      Hball, Hball + (size_t)NROWS*HID, Hball + (size_t)2*NROWS*HID,
      Hball + (size_t)3*NROWS*HID, Hball + (size_t)4*NROWS*HID,
      feat, W_14, b1, W_24, b2, w3, b3, out);
}

// Round 8
// 3165.760 us; speedup vs baseline: 2.0726x; 1.0853x over previous
//
#include <hip/hip_runtime.h>
#include <hip/hip_bf16.h>

typedef _Float16 f16x2 __attribute__((ext_vector_type(2)));

#define HID 300
#define NSEQ 64
#define NROWS 4096   // B*N = 64*64

union U { uint4 u; f16x2 h[4]; };

__device__ __forceinline__ float sigm(float x){ return 1.f/(1.f+__expf(-x)); }

__device__ __forceinline__ float fdot2a(f16x2 a, f16x2 b, float c){
#if __has_builtin(__builtin_amdgcn_fdot2)
  return __builtin_amdgcn_fdot2(a, b, c, false);
#else
  return c + (float)a.x*(float)b.x + (float)a.y*(float)b.y;
#endif
}

// Relaxed agent-scope ops: LLC-coherent, NO cache maintenance (no L2 flush).
__device__ __forceinline__ void xstore(float* p, float v){
  __hip_atomic_store(p, v, __ATOMIC_RELAXED, __HIP_MEMORY_SCOPE_AGENT);
}
__device__ __forceinline__ float xload(const float* p){
  return __hip_atomic_load(p, __ATOMIC_RELAXED, __HIP_MEMORY_SCOPE_AGENT);
}

// ---------------------------------------------------------------------------
// Merged repack: f32 -> fp16 pairs, [kg][outs][4 pairs] coalesced; also zeroes
// the pipeline sync counters + claim pools every launch.
// ---------------------------------------------------------------------------
__global__ void convert_all_kernel(
    const float* __restrict__ whh_c, const float* __restrict__ wih_p,
    const float* __restrict__ wih_c, const float* __restrict__ whh_p,
    const float* __restrict__ wr0,   const float* __restrict__ wr1,
    const float* __restrict__ w_in,  const float* __restrict__ w1,
    const float* __restrict__ w2,
    f16x2* __restrict__ W_M4, f16x2* __restrict__ WrT4, f16x2* __restrict__ W_P4,
    f16x2* __restrict__ W_H4, f16x2* __restrict__ W_14, f16x2* __restrict__ W_24,
    int* __restrict__ syncc)
{
  const int NA = 4*38*1800*4;
  const int NB = 4*38*600*4;
  const int NP = 4*38*1800*4;
  const int NH = 128*300*4;
  const int N1 = 318*304*4;
  const int N2 = 38*304*4;
  const int NS = 3*64*16 + 64;   // step counters + claim pools
  const int TOT = NA+NB+NP+NH+N1+N2+NS;
  for (int idx0 = blockIdx.x*blockDim.x + threadIdx.x; idx0 < TOT; idx0 += gridDim.x*blockDim.x){
    int idx = idx0;
    if (idx < NA){
      int l    = idx/(38*1800*4);
      int rem  = idx - l*(38*1800*4);
      int kg   = rem/(1800*4);
      int rem2 = rem - kg*(1800*4);
      int o = rem2>>2, s = rem2&3;
      int c = (kg*4+s)*2;
      float v0=0.f, v1=0.f;
      if (c < 300){
        const float* src = (o<900) ? (whh_c + ((size_t)l*900+o)*300)
                                   : (wih_p + ((size_t)l*900+(o-900))*300);
        v0 = src[c]; v1 = src[c+1];
      }
      f16x2 t; t.x=(_Float16)v0; t.y=(_Float16)v1;
      W_M4[idx] = t; continue;
    }
    idx -= NA;
    if (idx < NB){
      int l    = idx/(38*600*4);
      int rem  = idx - l*(38*600*4);
      int kg   = rem/(600*4);
      int rem2 = rem - kg*(600*4);
      int t6 = rem2>>2, s = rem2&3;
      int d = t6>>1, hh = t6&1;
      int c = (kg*4+s)*2;
      float v0=0.f, v1=0.f;
      if (c < 300){
        const float* src = hh ? (wr1 + ((size_t)l*300+d)*300)
                              : (wr0 + ((size_t)l*300+d)*300);
        v0 = src[c]; v1 = src[c+1];
      }
      f16x2 t; t.x=(_Float16)v0; t.y=(_Float16)v1;
      WrT4[idx] = t; continue;
    }
    idx -= NB;
    if (idx < NP){
      int l    = idx/(38*1800*4);
      int rem  = idx - l*(38*1800*4);
      int kg   = rem/(1800*4);
      int rem2 = rem - kg*(1800*4);
      int o = rem2>>2, s = rem2&3;
      int c = (kg*4+s)*2;
      float v0=0.f, v1=0.f;
      if (c < 300){
        const float* src = (o<900) ? (wih_c + ((size_t)l*900+o)*300)
                                   : (whh_p + ((size_t)l*900+(o-900))*300);
        v0 = src[c]; v1 = src[c+1];
      }
      f16x2 t; t.x=(_Float16)v0; t.y=(_Float16)v1;
      W_P4[idx] = t; continue;
    }
    idx -= NP;
    if (idx < NH){
      int kg  = idx/(300*4);
      int rem = idx - kg*(300*4);
      int o = rem>>2, s = rem&3;
      int c = (kg*4+s)*2;
      f16x2 t; t.x=(_Float16)w_in[(size_t)o*1024+c]; t.y=(_Float16)w_in[(size_t)o*1024+c+1];
      W_H4[idx] = t; continue;
    }
    idx -= NH;
    if (idx < N1){
      int kgg = idx/(304*4);
      int rem = idx - kgg*(304*4);
      int o = rem>>2, s = rem&3;
      int segbase, seglen, kgl;
      if (kgg < 190){ int seg = kgg/38; kgl = kgg - seg*38; segbase = seg*300; seglen = 300; }
      else { int kk = kgg-190; int sf = kk>>6; kgl = kk&63; segbase = 1500 + sf*512; seglen = 512; }
      int c = (kgl*4+s)*2;
      float v0=0.f, v1=0.f;
      if (o < 300 && c < seglen){
        v0 = w1[(size_t)o*2524 + segbase + c];
        if (c+1 < seglen) v1 = w1[(size_t)o*2524 + segbase + c + 1];
      }
      f16x2 t; t.x=(_Float16)v0; t.y=(_Float16)v1;
      W_14[idx] = t; continue;
    }
    idx -= N1;
    if (idx < N2){
      int kg = idx/(304*4);
      int rem = idx - kg*(304*4);
      int o = rem>>2, s = rem&3;
      int c = (kg*4+s)*2;
      float v0=0.f, v1=0.f;
      if (o < 300 && c < 300){ v0 = w2[(size_t)o*300+c]; v1 = w2[(size_t)o*300+c+1]; }
      f16x2 t; t.x=(_Float16)v0; t.y=(_Float16)v1;
      W_24[idx] = t; continue;
    }
    idx -= N2;
    syncc[idx] = 0;
  }
}

// ---------------------------------------------------------------------------
// H0 = relu(features @ w_in^T + b_in), coalesced fp16 weights.
// ---------------------------------------------------------------------------
__global__ __launch_bounds__(256) void h0_kernel(const float* __restrict__ feat,
    const f16x2* __restrict__ WH, const float* __restrict__ b_in, float* __restrict__ H0)
{
  const int tid = threadIdx.x;
  const int r0  = blockIdx.x*8;
  __shared__ f16x2 X[8][512];
  for (int t=tid; t<8*512; t+=256){
    int r=t>>9, p=t&511, c=2*p;
    f16x2 h; h.x=(_Float16)feat[(size_t)(r0+r)*1024+c];
    h.y=(_Float16)feat[(size_t)(r0+r)*1024+c+1];
    X[r][p]=h;
  }
  __syncthreads();
  const uint4* WHu = (const uint4*)WH;
  const int o0 = tid, o1 = tid+256;
  const bool h1v = (o1 < 300);
  float acc[2][8];
  #pragma unroll
  for (int j=0;j<2;j++)
    #pragma unroll
    for (int r=0;r<8;r++) acc[j][r]=0.f;
  for (int kg=0; kg<128; kg++){
    U w0, w1;
    w0.u = WHu[(size_t)kg*300 + o0];
    if (h1v) w1.u = WHu[(size_t)kg*300 + o1];
    #pragma unroll
    for (int r=0;r<8;r++){
      const f16x2* xp = &X[r][kg*4];
      f16x2 x0=xp[0],x1=xp[1],x2=xp[2],x3=xp[3];
      acc[0][r] = fdot2a(w0.h[3],x3, fdot2a(w0.h[2],x2, fdot2a(w0.h[1],x1, fdot2a(w0.h[0],x0, acc[0][r]))));
      if (h1v)
        acc[1][r] = fdot2a(w1.h[3],x3, fdot2a(w1.h[2],x2, fdot2a(w1.h[1],x1, fdot2a(w1.h[0],x0, acc[1][r]))));
    }
  }
  {
    float bb = b_in[o0];
    #pragma unroll
    for (int r=0;r<8;r++) H0[(size_t)(r0+r)*HID + o0] = fmaxf(acc[0][r]+bb, 0.f);
  }
  if (h1v){
    float bb = b_in[o1];
    #pragma unroll
    for (int r=0;r<8;r++) H0[(size_t)(r0+r)*HID + o1] = fmaxf(acc[1][r]+bb, 0.f);
  }
}

// ---------------------------------------------------------------------------
// Fused 4-layer pipelined scan, XCD-aware claimed placement.
// 256 WGs; each claims a (layer, chain): preferred layer = XCC_ID>>1 so each
// XCD serves ONE layer's 2.55 MB weight set (L2-resident); overflow pools
// guarantee complete assignment under any dispatch mapping. LDS padded >80KB
// to force 1 WG/CU (full per-CU L1 bandwidth, guaranteed spread).
// ---------------------------------------------------------------------------
__global__ __launch_bounds__(1024) void scan_pipe_kernel(
  float* __restrict__ Hball,
  const f16x2* __restrict__ W_M4, const f16x2* __restrict__ WrT4, const f16x2* __restrict__ W_P4,
  const float* __restrict__ bih_c, const float* __restrict__ bhh_c,
  const float* __restrict__ bih_p, const float* __restrict__ bhh_p,
  const float* __restrict__ gwq, const float* __restrict__ gwk, const float* __restrict__ gbv,
  const int* __restrict__ speakers, float* __restrict__ xrow, int* __restrict__ syncc)
{
  __shared__ _Float16 Hh[NSEQ][304];
  __shared__ float pre_s[1800];
  __shared__ float gates[1800];
  __shared__ float Mf[304];
  __shared__ f16x2 Mh[152];
  __shared__ f16x2 u01h[304];
  __shared__ float wgt[NSEQ];
  __shared__ float kd[NSEQ];
  __shared__ float red[320];
  __shared__ float xf[304];
  __shared__ f16x2 xh[152];
  __shared__ int   spk[NSEQ];
  __shared__ int   startA[NSEQ];
  __shared__ int   sLayer, sChain;
  __shared__ float pad_lds[6400];   // occupancy limiter: LDS > 80KB -> 1 WG/CU

  const int tid = threadIdx.x;

  // --- claim (layer, chain) with XCD-local preference ---
  if (tid == 0){
    int xcc = 0;
    asm volatile("s_getreg_b32 %0, hwreg(HW_REG_XCC_ID)" : "=s"(xcc));
    int pref = (xcc >> 1) & 3;
    int* claimc = syncc + 3*64*16;
    int l = 0, c = 0;
    #pragma unroll 1
    for (int t=0; t<4; ++t){
      int cand = (pref + t) & 3;
      int idx = __hip_atomic_fetch_add(&claimc[cand*16], 1, __ATOMIC_RELAXED, __HIP_MEMORY_SCOPE_AGENT);
      if (idx < 64){ l = cand; c = idx; break; }
    }
    sLayer = l; sChain = c;
  }
  __syncthreads();
  const int layer = sLayer;
  const int chain = sChain;
  const int base  = chain * NSEQ;

  const uint4* Wm4 = (const uint4*)(W_M4 + (size_t)layer*38*1800*4);
  const uint4* Wr4 = (const uint4*)(WrT4 + (size_t)layer*38*600*4);
  const uint4* Wp4 = (const uint4*)(W_P4 + (size_t)layer*38*1800*4);
  const float* HinB = Hball + (size_t)base*300;                       // layer 0 input
  float* HoutB = Hball + ((size_t)(layer+1)*NROWS + (size_t)base)*300;
  const float gb = gbv[layer];
  int* cntP = syncc + (layer*64 + chain)*16;
  int* cntC = (layer>0) ? (syncc + ((layer-1)*64 + chain)*16) : (int*)0;
  const float* xin  = xrow + (size_t)((layer-1)*64 + chain)*NSEQ*300; // layer>0
  float*       xout = xrow + (size_t)(layer*64 + chain)*NSEQ*300;     // layer<3

  // step-invariant per-thread regs
  float bcr=0,bcz=0,bcn=0,bpr=0,bpz=0,bpn=0,wkv=0;
  if (tid < 300){
    bcr=bhh_c[layer*900+tid]; bcz=bhh_c[layer*900+300+tid]; bcn=bhh_c[layer*900+600+tid];
    bpr=bih_p[layer*900+tid]; bpz=bih_p[layer*900+300+tid]; bpn=bih_p[layer*900+600+tid];
    wkv=gwk[layer*300+tid];
  }
  float wq0r=0, wq1r=0;
  if (tid < 150){ wq0r = gwq[layer*300+2*tid]; wq1r = gwq[layer*300+2*tid+1]; }
  const int pt  = tid - 64;        // pre-GEMV thread index (waves 1..15)
  const int po1 = pt, po2 = 960 + pt;
  const bool p2v = (pt >= 0) && (pt < 840);
  float pb1=0, pb2=0;
  if (tid >= 64){
    pb1 = (po1<900) ? bih_c[layer*900+po1] : bhh_p[layer*900+po1-900];
    if (p2v) pb2 = bhh_p[layer*900+po2-900];
  }
  const int o1 = tid, o2 = tid+1024;
  const bool dhas2 = (o2 < 1800);

  if (tid < NSEQ) spk[tid] = speakers[base+tid];
  if (tid >= 300 && tid < 320) red[tid]=0.f;
  if (tid >= 300 && tid < 304) xf[tid]=0.f;
  for (int t=tid; t<1800; t+=1024) gates[t]=0.f;
  if (tid < 304) Mf[tid]=0.f;
  if (tid < 2){
    f16x2 z; z.x=(_Float16)0.f; z.y=(_Float16)0.f;
    Mh[150+tid]=z; xh[150+tid]=z; u01h[150+tid]=z; u01h[302+tid]=z;
  }
  __syncthreads();
  if (tid < NSEQ){
    int s=0; for (int j=tid-1;j>=0;--j) if (spk[j]==spk[tid]){s=j;break;}
    startA[tid]=s;
  }
  if ((unsigned)spk[0] == 0xDEADBEEFu) pad_lds[tid] = 0.f;  // keep pad alive (never true)
  if (layer>0 && tid==0){
    while (__hip_atomic_load(cntC, __ATOMIC_RELAXED, __HIP_MEMORY_SCOPE_AGENT) < 1)
      __builtin_amdgcn_s_sleep(8);
  }
  __syncthreads();

  for (int i=0; i<NSEQ; ++i){
    // R: receive/load input row i -> xf (f32) + xh (fp16) + qd partial products
    if (tid < 150){
      float x0, x1;
      if (layer==0){
        float2 v = *(const float2*)(HinB + (size_t)i*300 + 2*tid);
        x0=v.x; x1=v.y;
      } else {
        x0 = xload(xin + (size_t)i*300 + 2*tid);
        x1 = xload(xin + (size_t)i*300 + 2*tid + 1);
      }
      xf[2*tid]=x0; xf[2*tid+1]=x1;
      f16x2 h; h.x=(_Float16)x0; h.y=(_Float16)x1; xh[tid]=h;
      red[tid] = x0*wq0r + x1*wq1r;
    }
    __syncthreads();
    // P: fused pre-GEMV on waves 1..15  ||  A: qd-reduce + softmax on wave 0
    if (tid >= 64){
      float a0=0,a1=0,a2=0,a3=0, e0=0,e1=0,e2=0,e3=0;
      for (int kg=0;kg<38;kg++){
        U v0, v1;
        v0.u = Wp4[(size_t)kg*1800 + po1];
        if (p2v) v1.u = Wp4[(size_t)kg*1800 + po2];
        f16x2 x0=xh[kg*4+0],x1=xh[kg*4+1],x2=xh[kg*4+2],x3=xh[kg*4+3];
        a0=fdot2a(v0.h[0],x0,a0); a1=fdot2a(v0.h[1],x1,a1);
        a2=fdot2a(v0.h[2],x2,a2); a3=fdot2a(v0.h[3],x3,a3);
        if (p2v){ e0=fdot2a(v1.h[0],x0,e0); e1=fdot2a(v1.h[1],x1,e1);
                  e2=fdot2a(v1.h[2],x2,e2); e3=fdot2a(v1.h[3],x3,e3); }
      }
      pre_s[po1] = (a0+a1)+(a2+a3) + pb1;
      if (p2v) pre_s[po2] = (e0+e1)+(e2+e3) + pb2;
    } else if (i > 0){
      float s = red[tid] + red[tid+64] + ((tid<22)? red[tid+128] : 0.f);
      #pragma unroll
      for (int o=32;o>0;o>>=1) s += __shfl_xor(s,o);
      const float q = s;
      const int st = startA[i];
      const bool in = (tid>=st) && (tid<i);
      float a = in ? (q + kd[tid] + gb) : -3.0e38f;
      float m = a;
      #pragma unroll
      for (int o=32;o>0;o>>=1) m = fmaxf(m,__shfl_xor(m,o));
      float e = in ? __expf(a-m) : 0.f;
      float ss = e;
      #pragma unroll
      for (int o=32;o>0;o>>=1) ss += __shfl_xor(ss,o);
      wgt[tid] = e/ss;
    }
    __syncthreads();
    if (i > 0){
      // B: u0 (same-speaker) / u1 (other) weighted history sums
      if (tid < 600){
        const int d  = (tid<300)? tid : (tid-300);
        const int wh = (tid>=300);
        const int st = startA[i]; const int ms = spk[i];
        float u=0.f;
        for (int j=st;j<i;++j){
          float sel = ((spk[j]==ms) != (wh!=0)) ? 1.f : 0.f;
          u += sel*wgt[j]*(float)Hh[j][d];
        }
        ((_Float16*)u01h)[(wh?304:0) + d] = (_Float16)u;
      }
      __syncthreads();
      // C: M = wr0@u0 + wr1@u1 ; pair-combine + Mh pack via in-wave shuffles
      if (tid < 600){
        const int hh = tid&1;
        const f16x2* uu = (const f16x2*)u01h + hh*152;
        float a0=0,a1=0,a2=0,a3=0;
        for (int kg=0;kg<38;kg++){
          U v; v.u = Wr4[(size_t)kg*600 + tid];
          a0=fdot2a(v.h[0],uu[kg*4+0],a0);
          a1=fdot2a(v.h[1],uu[kg*4+1],a1);
          a2=fdot2a(v.h[2],uu[kg*4+2],a2);
          a3=fdot2a(v.h[3],uu[kg*4+3],a3);
        }
        float a = (a0+a1)+(a2+a3);
        float m2 = a + __shfl_xor(a,1);         // M[d], d = tid>>1
        if ((tid&1)==0) Mf[tid>>1] = m2;
        float mo = __shfl_xor(m2,2);            // M[d^1]
        if ((tid&3)==0){ f16x2 mh; mh.x=(_Float16)m2; mh.y=(_Float16)mo; Mh[tid>>2]=mh; }
      }
      __syncthreads();
      // D: gates = [whh_c ; wih_p] @ M (1800 rows, 2/thread)
      {
        float a0=0,a1=0,a2=0,a3=0, e0=0,e1=0,e2=0,e3=0;
        for (int kg=0;kg<38;kg++){
          U v0, v1;
          v0.u = Wm4[(size_t)kg*1800 + o1];
          if (dhas2) v1.u = Wm4[(size_t)kg*1800 + o2];
          f16x2 m0=Mh[kg*4+0], m1=Mh[kg*4+1], m2=Mh[kg*4+2], m3=Mh[kg*4+3];
          a0=fdot2a(v0.h[0],m0,a0); a1=fdot2a(v0.h[1],m1,a1);
          a2=fdot2a(v0.h[2],m2,a2); a3=fdot2a(v0.h[3],m3,a3);
          if (dhas2){ e0=fdot2a(v1.h[0],m0,e0); e1=fdot2a(v1.h[1],m1,e1);
                      e2=fdot2a(v1.h[2],m2,e2); e3=fdot2a(v1.h[3],m3,e3); }
        }
        gates[o1] = (a0+a1)+(a2+a3);
        if (dhas2) gates[o2] = (e0+e1)+(e2+e3);
      }
      __syncthreads();
    }
    // E: GRU combine; write Hout + own history + publish to consumer
    if (tid < 300){
      const float M = Mf[tid];
      float r  = sigm(pre_s[tid] + gates[tid] + bcr);
      float z  = sigm(pre_s[300+tid] + gates[300+tid] + bcz);
      float n  = tanhf(pre_s[600+tid] + r*(gates[600+tid]+bcn));
      float C  = (1.f-z)*n + z*M;
      float rp = sigm(gates[900+tid]+bpr + pre_s[900+tid]);
      float zp = sigm(gates[1200+tid]+bpz + pre_s[1200+tid]);
      float np = tanhf(gates[1500+tid]+bpn + rp*pre_s[1500+tid]);
      float qv = xf[tid];
      float P  = (1.f-zp)*np + zp*qv;
      float h  = C + P;
      HoutB[(size_t)i*300 + tid] = h;
      Hh[i][tid] = (_Float16)h;
      red[tid] = h*wkv;
      if (layer<3) xstore(xout + (size_t)i*300 + tid, h);
    }
    asm volatile("s_waitcnt vmcnt(0)" ::: "memory");   // drain publish before counting
    __syncthreads();
    // F: kd[i]; bump own counter; poll producer for next row
    if (tid < 64){
      float s = red[tid]+red[tid+64]+red[tid+128]+red[tid+192]+red[tid+256];
      #pragma unroll
      for (int o=32;o>0;o>>=1) s += __shfl_xor(s,o);
      if (tid==0) kd[i]=s;
    }
    if (tid==0){
      if (layer<3) __hip_atomic_fetch_add(cntP, 1, __ATOMIC_RELAXED, __HIP_MEMORY_SCOPE_AGENT);
      if (layer>0 && i<63){
        while (__hip_atomic_load(cntC, __ATOMIC_RELAXED, __HIP_MEMORY_SCOPE_AGENT) < i+2)
          __builtin_amdgcn_s_sleep(8);
      }
    }
    __syncthreads();
  }
}

// ---------------------------------------------------------------------------
// Head with fp16-dot2 GEMMs (unchanged).
// ---------------------------------------------------------------------------
__global__ __launch_bounds__(256) void head_kernel(
  const float* __restrict__ H0, const float* __restrict__ Hl1,
  const float* __restrict__ Hl2, const float* __restrict__ Hl3,
  const float* __restrict__ Hl4, const float* __restrict__ feat,
  const f16x2* __restrict__ W14, const float* __restrict__ b1,
  const f16x2* __restrict__ W24, const float* __restrict__ b2,
  const float* __restrict__ w3, const float* __restrict__ b3,
  float* __restrict__ out)
{
  const int tid = threadIdx.x;
  const int r0  = blockIdx.x*16;
  __shared__ f16x2 Xh[16*256];
  __shared__ _Float16 h1h[16*304];
  __shared__ float S2[16*304];
  const uint4* W14u = (const uint4*)W14;
  const uint4* W24u = (const uint4*)W24;

  float acc0[16], acc1[16];
  #pragma unroll
  for (int r=0;r<16;r++){ acc0[r]=0.f; acc1[r]=0.f; }
  const int o  = tid;
  const int o2 = tid + 256;
  const bool has2 = (o2 < 300);

  #pragma unroll
  for (int seg=0; seg<7; seg++){
    const float* src = (seg==0)?H0:(seg==1)?Hl1:(seg==2)?Hl2:(seg==3)?Hl3:(seg==4)?Hl4:feat;
    if (seg < 5){
      for (int t=tid; t<16*152; t+=256){
        int r=t/152, p=t-r*152, c=2*p;
        float v0 = (c<300)? src[(size_t)(r0+r)*300 + c] : 0.f;
        float v1 = (c+1<300)? src[(size_t)(r0+r)*300 + c+1] : 0.f;
        f16x2 h; h.x=(_Float16)v0; h.y=(_Float16)v1;
        Xh[r*256+p] = h;
      }
    } else {
      const int cb = (seg-5)*512;
      for (int t=tid; t<16*256; t+=256){
        int r=t>>8, p=t&255;
        float v0 = src[(size_t)(r0+r)*1024 + cb + 2*p];
        float v1 = src[(size_t)(r0+r)*1024 + cb + 2*p+1];
        f16x2 h; h.x=(_Float16)v0; h.y=(_Float16)v1;
        Xh[r*256+p] = h;
      }
    }
    __syncthreads();
    const int kgs = (seg<5)?38:64;
    const int kgo = (seg<5)? seg*38 : 190+(seg-5)*64;
    if (o < 300){
      for (int kg=0; kg<kgs; kg++){
        U a, b;
        a.u = W14u[(size_t)(kgo+kg)*304 + o];
        if (has2) b.u = W14u[(size_t)(kgo+kg)*304 + o2];
        #pragma unroll
        for (int r=0;r<16;r++){
          const f16x2* xp = &Xh[r*256 + kg*4];
          float t0 = fdot2a(a.h[0], xp[0], 0.f);
          t0 = fdot2a(a.h[1], xp[1], t0);
          t0 = fdot2a(a.h[2], xp[2], t0);
          t0 = fdot2a(a.h[3], xp[3], t0);
          acc0[r] += t0;
          if (has2){
            float t1 = fdot2a(b.h[0], xp[0], 0.f);
            t1 = fdot2a(b.h[1], xp[1], t1);
            t1 = fdot2a(b.h[2], xp[2], t1);
            t1 = fdot2a(b.h[3], xp[3], t1);
            acc1[r] += t1;
          }
        }
      }
    }
    __syncthreads();
  }
  if (o < 300){
    float bb = b1[o];
    #pragma unroll
    for (int r=0;r<16;r++) h1h[r*304+o] = (_Float16)fmaxf(acc0[r]+bb, 0.f);
  }
  if (has2){
    float bb = b1[o2];
    #pragma unroll
    for (int r=0;r<16;r++) h1h[r*304+o2] = (_Float16)fmaxf(acc1[r]+bb, 0.f);
  }
  if (tid < 4){
    #pragma unroll
    for (int r=0;r<16;r++) h1h[r*304+300+tid] = (_Float16)0.f;
  }
  __syncthreads();
  #pragma unroll
  for (int r=0;r<16;r++){ acc0[r]=0.f; acc1[r]=0.f; }
  if (o < 300){
    for (int kg=0; kg<38; kg++){
      U a, b;
      a.u = W24u[(size_t)kg*304 + o];
      if (has2) b.u = W24u[(size_t)kg*304 + o2];
      #pragma unroll
      for (int r=0;r<16;r++){
        const f16x2* xp = (const f16x2*)&h1h[r*304] + kg*4;
        float t0 = fdot2a(a.h[0], xp[0], 0.f);
        t0 = fdot2a(a.h[1], xp[1], t0);
        t0 = fdot2a(a.h[2], xp[2], t0);
        t0 = fdot2a(a.h[3], xp[3], t0);
        acc0[r] += t0;
        if (has2){
          float t1 = fdot2a(b.h[0], xp[0], 0.f);
          t1 = fdot2a(b.h[1], xp[1], t1);
          t1 = fdot2a(b.h[2], xp[2], t1);
          t1 = fdot2a(b.h[3], xp[3], t1);
          acc1[r] += t1;
        }
      }
    }
  }
  __syncthreads();
  if (o < 300){
    float bb = b2[o];
    #pragma unroll
    for (int r=0;r<16;r++) S2[r*304+o] = fmaxf(acc0[r]+bb, 0.f);
  }
  if (has2){
    float bb = b2[o2];
    #pragma unroll
    for (int r=0;r<16;r++) S2[r*304+o2] = fmaxf(acc1[r]+bb, 0.f);
  }
  __syncthreads();
  if (tid < 16*7){
    int r = tid/7, c = tid - r*7;
    float s = b3[c];
    const float* wrow = w3 + (size_t)c*HID;
    for (int k=0;k<HID;k++) s += wrow[k]*S2[r*304+k];
    out[(size_t)(r0+r)*7 + c] = s;
  }
}

// ---------------------------------------------------------------------------
extern "C" void kernel_launch(void* const* d_in, const int* in_sizes, int n_in,
                              void* d_out, int out_size, void* d_ws, size_t ws_size,
                              hipStream_t stream)
{
  (void)in_sizes; (void)n_in; (void)out_size; (void)ws_size;
  const float* feat  = (const float*)d_in[0];
  const int*   spk   = (const int*)d_in[1];
  const float* w_in  = (const float*)d_in[2];
  const float* b_in  = (const float*)d_in[3];
  const float* gwq   = (const float*)d_in[4];
  const float* gwk   = (const float*)d_in[5];
  const float* gb    = (const float*)d_in[6];
  const float* wr0   = (const float*)d_in[7];
  const float* wr1   = (const float*)d_in[8];
  const float* wih_c = (const float*)d_in[9];
  const float* whh_c = (const float*)d_in[10];
  const float* bih_c = (const float*)d_in[11];
  const float* bhh_c = (const float*)d_in[12];
  const float* wih_p = (const float*)d_in[13];
  const float* whh_p = (const float*)d_in[14];
  const float* bih_p = (const float*)d_in[15];
  const float* bhh_p = (const float*)d_in[16];
  const float* w1    = (const float*)d_in[17];
  const float* b1    = (const float*)d_in[18];
  const float* w2    = (const float*)d_in[19];
  const float* b2    = (const float*)d_in[20];
  const float* w3    = (const float*)d_in[21];
  const float* b3    = (const float*)d_in[22];
  float* out = (float*)d_out;

  char* ws = (char*)d_ws;
  size_t off = 0;
  auto alloc = [&](size_t bytes)->void*{
    void* p = ws + off;
    off += (bytes + 255) & ~(size_t)255;
    return p;
  };
  f16x2* W_M4 = (f16x2*)alloc((size_t)4*38*1800*4 * sizeof(f16x2));
  f16x2* WrT4 = (f16x2*)alloc((size_t)4*38*600*4  * sizeof(f16x2));
  f16x2* W_P4 = (f16x2*)alloc((size_t)4*38*1800*4 * sizeof(f16x2));
  f16x2* W_H4 = (f16x2*)alloc((size_t)128*300*4   * sizeof(f16x2));
  f16x2* W_14 = (f16x2*)alloc((size_t)318*304*4   * sizeof(f16x2));
  f16x2* W_24 = (f16x2*)alloc((size_t)38*304*4    * sizeof(f16x2));
  float* Hball = (float*)alloc((size_t)5*NROWS*HID*sizeof(float));
  float* xrow  = (float*)alloc((size_t)3*64*NSEQ*HID*sizeof(float));
  int*   syncc = (int*)alloc((size_t)(3*64*16 + 64)*sizeof(int));

  {
    const int tot = 4*38*1800*4 + 4*38*600*4 + 4*38*1800*4 + 128*300*4
                  + 318*304*4 + 38*304*4 + (3*64*16 + 64);
    convert_all_kernel<<<(tot+255)/256, 256, 0, stream>>>(whh_c, wih_p, wih_c, whh_p,
        wr0, wr1, w_in, w1, w2, W_M4, WrT4, W_P4, W_H4, W_14, W_24, syncc);
  }
  h0_kernel<<<NROWS/8, 256, 0, stream>>>(feat, W_H4, b_in, Hball);

  scan_pipe_kernel<<<256, 1024, 0, stream>>>(Hball, W_M4, WrT4, W_P4,
      bih_c, bhh_c, bih_p, bhh_p, gwq, gwk, gb, spk, xrow, syncc);

  head_kernel<<<NROWS/16, 256, 0, stream>>>(
      Hball, Hball + (size_t)NROWS*HID, Hball + (size_t)2*NROWS*HID,
      Hball + (size_t)3*NROWS*HID, Hball + (size_t)4*NROWS*HID,
      feat, W_14, b1, W_24, b2, w3, b3, out);
}